// Round 3
// baseline (290.571 us; speedup 1.0000x reference)
//
#include <hip/hip_runtime.h>
#include <hip/hip_bf16.h>

// VSSBlock: B=2 H=64 W=64 C=192 DM=384 N=16 R=12 K=4 L=4096
// R11: revert R10's LDS staging (regressed: convoy + scattered staging); scans back to
//      R9 broadcast-VMEM form; ONE change vs R9: segment split S=128/T=32 -> S=256/T=16
//      (2x wave residency for latency hiding). Combine keeps pow16 fast path.

typedef __attribute__((ext_vector_type(8))) short short8;     // 8 bf16 = 4 VGPRs
typedef __attribute__((ext_vector_type(4))) float floatx4;    // fp32 accum frag

// ---------------- LayerNorm (pre-norm, eps 1e-6), C=192 -> bf16 ----------------
__global__ __launch_bounds__(256) void k_ln(const float* __restrict__ in,
                                            const float* __restrict__ g,
                                            const float* __restrict__ be,
                                            __hip_bfloat16* __restrict__ out) {
  int row = blockIdx.x * 4 + (threadIdx.x >> 6);
  int lane = threadIdx.x & 63;
  const float* x = in + (long)row * 192;
  float v0 = x[lane], v1 = x[lane + 64], v2 = x[lane + 128];
  float s = v0 + v1 + v2;
  float s2 = v0 * v0 + v1 * v1 + v2 * v2;
  #pragma unroll
  for (int o = 32; o > 0; o >>= 1) { s += __shfl_xor(s, o); s2 += __shfl_xor(s2, o); }
  float mu = s * (1.f / 192.f);
  float var = s2 * (1.f / 192.f) - mu * mu;
  float r = rsqrtf(var + 1e-6f);
  __hip_bfloat16* op = out + (long)row * 192;
  op[lane]       = __float2bfloat16((v0 - mu) * r * g[lane]       + be[lane]);
  op[lane + 64]  = __float2bfloat16((v1 - mu) * r * g[lane + 64]  + be[lane + 64]);
  op[lane + 128] = __float2bfloat16((v2 - mu) * r * g[lane + 128] + be[lane + 128]);
}

// ---------------- pack weights -> bf16, transposed to (N x K) ----------------
__global__ __launch_bounds__(256) void k_packw(const float* __restrict__ ipw,
                                               const float* __restrict__ xpw,
                                               const float* __restrict__ opw,
                                               __hip_bfloat16* __restrict__ Wt1,
                                               __hip_bfloat16* __restrict__ Wt2,
                                               __hip_bfloat16* __restrict__ Wt3) {
  int idx = blockIdx.x * 256 + threadIdx.x;
  if (idx < 147456) {                       // Wt1[n][k] = ipw[k][n]
    int n = idx / 192, k = idx - n * 192;
    Wt1[idx] = __float2bfloat16(ipw[(long)k * 768 + n]);
  } else if (idx < 147456 + 73728) {        // Wt2[j][d]
    int t = idx - 147456;
    int j = t / 384;
    float v = (j < 176) ? xpw[t] : 0.f;
    Wt2[t] = __float2bfloat16(v);
  } else if (idx < 147456 + 73728 + 73728) {// Wt3[n][k] = opw[k][n]
    int t = idx - 147456 - 73728;
    int n = t / 384, k = t - n * 384;
    Wt3[t] = __float2bfloat16(opw[(long)k * 192 + n]);
  }
}

// direction map (involutions): pixel p <-> scan position l
__device__ __forceinline__ int inv_dir(int k, int p) {
  int pt = ((p & 63) << 6) | (p >> 6);
  if (k == 0) return p;
  if (k == 1) return pt;
  if (k == 2) return 4095 - p;
  return 4095 - pt;
}
__device__ __forceinline__ int dir_pix(int k, int l) { return inv_dir(k, l); }

// ---------------- bf16 MFMA GEMM: 64x64 tile, BK=64, XOR-swizzled LDS ----------------
template <int EPI>
__global__ __launch_bounds__(256) void k_gemm_mfma(const __hip_bfloat16* __restrict__ A,
                                                   const __hip_bfloat16* __restrict__ Bt,
                                                   const float* __restrict__ Res,
                                                   float* __restrict__ Co,
                                                   __hip_bfloat16* __restrict__ CoB,
                                                   __hip_bfloat16* __restrict__ Co2B,
                                                   float* __restrict__ dtsS,
                                                   float* __restrict__ BsS,
                                                   float* __restrict__ CsS,
                                                   int M, int N, int Kk) {
  __shared__ __align__(16) short As[64 * 64];
  __shared__ __align__(16) short Bs[64 * 64];
  int tid = threadIdx.x;
  int wave = tid >> 6, lane = tid & 63;
  int mlane = lane & 15, quad = lane >> 4;
  int row0 = blockIdx.y * 64, col0 = blockIdx.x * 64;
  int wr = wave & 1, wc = wave >> 1;
  floatx4 acc[2][2];
  #pragma unroll
  for (int mi = 0; mi < 2; mi++)
    #pragma unroll
    for (int ni = 0; ni < 2; ni++) acc[mi][ni] = (floatx4){0.f, 0.f, 0.f, 0.f};

  for (int k0 = 0; k0 < Kk; k0 += 64) {
    #pragma unroll
    for (int c = tid; c < 512; c += 256) {
      int r = c >> 3, j = c & 7;
      *(float4*)&As[r * 64 + ((j ^ (r & 7)) << 3)] =
          *(const float4*)&A[(long)(row0 + r) * Kk + k0 + j * 8];
    }
    #pragma unroll
    for (int c = tid; c < 512; c += 256) {
      int r = c >> 3, j = c & 7;
      *(float4*)&Bs[r * 64 + ((j ^ (r & 7)) << 3)] =
          *(const float4*)&Bt[(long)(col0 + r) * Kk + k0 + j * 8];
    }
    __syncthreads();
    short8 af[2][2], bf[2][2];
    #pragma unroll
    for (int mi = 0; mi < 2; mi++) {
      int r = wr * 32 + mi * 16 + mlane;
      #pragma unroll
      for (int kk = 0; kk < 2; kk++) {
        int jx = (kk * 4 + quad) ^ (r & 7);
        af[mi][kk] = *(const short8*)&As[r * 64 + jx * 8];
      }
    }
    #pragma unroll
    for (int ni = 0; ni < 2; ni++) {
      int rn = wc * 32 + ni * 16 + mlane;
      #pragma unroll
      for (int kk = 0; kk < 2; kk++) {
        int jx = (kk * 4 + quad) ^ (rn & 7);
        bf[ni][kk] = *(const short8*)&Bs[rn * 64 + jx * 8];
      }
    }
    #pragma unroll
    for (int kk = 0; kk < 2; kk++)
      #pragma unroll
      for (int mi = 0; mi < 2; mi++)
        #pragma unroll
        for (int ni = 0; ni < 2; ni++)
          acc[mi][ni] = __builtin_amdgcn_mfma_f32_16x16x32_bf16(af[mi][kk], bf[ni][kk],
                                                                acc[mi][ni], 0, 0, 0);
    __syncthreads();
  }
  // C/D layout: col=lane&15, row=quad*4+reg  [m89-verified]
  #pragma unroll
  for (int mi = 0; mi < 2; mi++) {
    #pragma unroll
    for (int ni = 0; ni < 2; ni++) {
      int cc = col0 + wc * 32 + ni * 16 + mlane;
      #pragma unroll
      for (int i = 0; i < 4; i++) {
        int rr = row0 + wr * 32 + mi * 16 + quad * 4 + i;
        float v = acc[mi][ni][i];
        if (EPI == 1) {
          Co[(long)rr * N + cc] = v + Res[(long)rr * N + cc];
        } else if (EPI == 2) {
          if (cc < 384) CoB[(long)rr * 384 + cc] = __float2bfloat16(v);
          else          Co2B[(long)rr * 384 + (cc - 384)] = __float2bfloat16(v);
        } else {  // EPI == 3: pixel-order x_dbl split -> coalesced stores
          if (cc < 176) {
            int k4 = (cc >= 132) ? 3 : (cc >= 88) ? 2 : (cc >= 44) ? 1 : 0;
            int c = cc - k4 * 44;
            int b = rr >> 12, p = rr & 4095;
            long lbase = ((long)((b << 2) + k4) << 12) + p;   // pixel order
            if (c < 12)      dtsS[lbase * 12 + c] = v;
            else if (c < 28) BsS[lbase * 16 + (c - 12)] = v;
            else             CsS[lbase * 16 + (c - 28)] = v;
          }
        }
      }
    }
  }
}

// ---------------- depthwise 3x3 conv + bias + SiLU; bf16 in, bf16 out ----------------
__global__ __launch_bounds__(384) void k_conv(const __hip_bfloat16* __restrict__ xbufB,
                                              const float* __restrict__ cw,
                                              const float* __restrict__ cb,
                                              __hip_bfloat16* __restrict__ xcb) {
  int row = blockIdx.x;
  int b = row >> 12, p = row & 4095;
  int h = p >> 6, w0 = p & 63;
  int d = threadIdx.x;
  float acc = cb[d];
  const float* wt = cw + d * 9;
  #pragma unroll
  for (int dh = -1; dh <= 1; dh++) {
    int hh = h + dh;
    if (hh < 0 || hh > 63) continue;
    #pragma unroll
    for (int dw = -1; dw <= 1; dw++) {
      int ww = w0 + dw;
      if (ww < 0 || ww > 63) continue;
      acc += __bfloat162float(xbufB[((long)(b << 12) + (hh << 6) + ww) * 384 + d])
             * wt[(dh + 1) * 3 + (dw + 1)];
    }
  }
  float sg = 1.f / (1.f + __expf(-acc));
  xcb[(long)row * 384 + d] = __float2bfloat16(acc * sg);
}

// powers: pws[n] = r^(n+1), log-depth pairing
__device__ __forceinline__ void pow16(float r, float* pws) {
  pws[0] = r;
  #pragma unroll
  for (int n = 1; n < 16; n++) {
    int m = n + 1, c = (m + 1) / 2, f = m - c;
    pws[n] = pws[c - 1] * pws[f - 1];
  }
}

// ---------------- scan pass 0: SEG segments x T steps; E[16] + scalar cumDelta ----------------
template <int T>
__global__ __launch_bounds__(384) void k_scan0(
    const float* __restrict__ dtsS, const float* __restrict__ BsS,
    const __hip_bfloat16* __restrict__ xcb,
    const float* __restrict__ A_logs, const float* __restrict__ dt_w,
    const float* __restrict__ dt_b,
    float* __restrict__ Eb, float* __restrict__ Dend) {
  constexpr int SEG = 4096 / T;
  int bid = blockIdx.x;
  int s = bid & (SEG - 1), bk = bid / SEG;
  int k = bk & 3, b = bk >> 2;
  int d = threadIdx.x;
  float w[12];
  const float* dwp = dt_w + ((long)(k * 384) + d) * 12;
  #pragma unroll
  for (int r = 0; r < 12; r++) w[r] = dwp[r];
  float db = dt_b[k * 384 + d];
  const float* al = A_logs + ((long)(k * 384) + d) * 16;
  bool pw = true;
  float av[16];
  #pragma unroll
  for (int n = 0; n < 16; n++) {
    float a = __expf(al[n]);
    av[n] = -a;
    pw = pw && (fabsf(a - (float)(n + 1)) < 1e-3f);
  }
  float h[16];
  #pragma unroll
  for (int n = 0; n < 16; n++) h[n] = 0.f;
  float cum = 0.f;
  long bpk = (long)bk << 12;
  long bpix = (long)(b << 12);

  if (pw) {
    #pragma unroll 4
    for (int t = 0; t < T; t++) {
      int p = dir_pix(k, s * T + t);
      const float4* dq = (const float4*)(dtsS + (bpk + p) * 12);
      float4 q0 = dq[0], q1 = dq[1], q2 = dq[2];
      float x = db + q0.x * w[0] + q0.y * w[1] + q0.z * w[2] + q0.w * w[3]
                   + q1.x * w[4] + q1.y * w[5] + q1.z * w[6] + q1.w * w[7]
                   + q2.x * w[8] + q2.y * w[9] + q2.z * w[10] + q2.w * w[11];
      float e = __expf(x);
      float delta = (x > 15.f) ? x : __logf(1.f + e);
      cum += delta;
      float u = __bfloat162float(xcb[(bpix + p) * 384 + d]);
      float du = delta * u;
      float rr = __builtin_amdgcn_rcpf(1.f + e);  // exp(-softplus(x))
      float pws[16]; pow16(rr, pws);
      const float4* Bq = (const float4*)(BsS + (bpk + p) * 16);
      float4 b0 = Bq[0], b1 = Bq[1], b2 = Bq[2], b3 = Bq[3];
      float Bl[16] = {b0.x, b0.y, b0.z, b0.w, b1.x, b1.y, b1.z, b1.w,
                      b2.x, b2.y, b2.z, b2.w, b3.x, b3.y, b3.z, b3.w};
      #pragma unroll
      for (int n = 0; n < 16; n++) h[n] = pws[n] * h[n] + du * Bl[n];
    }
  } else {
    for (int t = 0; t < T; t++) {
      int p = dir_pix(k, s * T + t);
      const float4* dq = (const float4*)(dtsS + (bpk + p) * 12);
      float4 q0 = dq[0], q1 = dq[1], q2 = dq[2];
      float x = db + q0.x * w[0] + q0.y * w[1] + q0.z * w[2] + q0.w * w[3]
                   + q1.x * w[4] + q1.y * w[5] + q1.z * w[6] + q1.w * w[7]
                   + q2.x * w[8] + q2.y * w[9] + q2.z * w[10] + q2.w * w[11];
      float e = __expf(x);
      float delta = (x > 15.f) ? x : __logf(1.f + e);
      cum += delta;
      float u = __bfloat162float(xcb[(bpix + p) * 384 + d]);
      float du = delta * u;
      const float4* Bq = (const float4*)(BsS + (bpk + p) * 16);
      float4 b0 = Bq[0], b1 = Bq[1], b2 = Bq[2], b3 = Bq[3];
      float Bl[16] = {b0.x, b0.y, b0.z, b0.w, b1.x, b1.y, b1.z, b1.w,
                      b2.x, b2.y, b2.z, b2.w, b3.x, b3.y, b3.z, b3.w};
      #pragma unroll
      for (int n = 0; n < 16; n++) {
        float dA = __expf(delta * av[n]);
        h[n] = dA * h[n] + du * Bl[n];
      }
    }
  }
  long g = (long)bk * SEG + s;
  float* Ep = Eb + g * 6144 + d * 16;
  #pragma unroll
  for (int n = 0; n < 16; n++) Ep[n] = h[n];
  Dend[g * 384 + d] = cum;
}

// ---------------- combine: Kogge-Stone over SEG segments; pow16 trick ----------------
template <int SEG>
__global__ __launch_bounds__(SEG) void k_combine(float* __restrict__ Eb,
                                                 const float* __restrict__ Dend,
                                                 const float* __restrict__ A_logs) {
  int bid = blockIdx.x;            // bk*384 + d, 3072 blocks
  int bk = bid / 384;
  int d = bid - bk * 384;
  int k = bk & 3;
  int s = threadIdx.x;             // segment 0..SEG-1
  const float* al = A_logs + ((long)(k * 384) + d) * 16;
  bool pw = true;
  float av[16];
  #pragma unroll
  for (int n = 0; n < 16; n++) {
    float a = __expf(al[n]);
    av[n] = -a;
    pw = pw && (fabsf(a - (float)(n + 1)) < 1e-3f);
  }

  long ebase = ((long)bk * SEG + s) * 6144 + d * 16;
  float e[16];
  *(float4*)&e[0]  = *(const float4*)&Eb[ebase + 0];
  *(float4*)&e[4]  = *(const float4*)&Eb[ebase + 4];
  *(float4*)&e[8]  = *(const float4*)&Eb[ebase + 8];
  *(float4*)&e[12] = *(const float4*)&Eb[ebase + 12];
  float sig = Dend[((long)bk * SEG + s) * 384 + d];

  __shared__ float sE[SEG][17];    // [s][0]=sigma, [s][1..16]=e
  sE[s][0] = sig;
  #pragma unroll
  for (int n = 0; n < 16; n++) sE[s][1 + n] = e[n];
  __syncthreads();

  for (int o = 1; o < SEG; o <<= 1) {
    float ps = 0.f, pe[16];
    bool act = (s >= o);
    if (act) {
      ps = sE[s - o][0];
      #pragma unroll
      for (int n = 0; n < 16; n++) pe[n] = sE[s - o][1 + n];
    }
    __syncthreads();
    if (act) {
      if (pw) {
        float rc = __expf(-sig);
        float pwr[16]; pow16(rc, pwr);      // pwr[n] = exp(av[n]*sig), av[n]=-(n+1)
        #pragma unroll
        for (int n = 0; n < 16; n++) e[n] += pwr[n] * pe[n];
      } else {
        #pragma unroll
        for (int n = 0; n < 16; n++) e[n] += __expf(av[n] * sig) * pe[n];
      }
      sig += ps;
      sE[s][0] = sig;
      #pragma unroll
      for (int n = 0; n < 16; n++) sE[s][1 + n] = e[n];
    }
    __syncthreads();
  }

  float ho[16];
  if (s == 0) {
    #pragma unroll
    for (int n = 0; n < 16; n++) ho[n] = 0.f;
  } else {
    #pragma unroll
    for (int n = 0; n < 16; n++) ho[n] = sE[s - 1][1 + n];
  }
  *(float4*)&Eb[ebase + 0]  = *(float4*)&ho[0];
  *(float4*)&Eb[ebase + 4]  = *(float4*)&ho[4];
  *(float4*)&Eb[ebase + 8]  = *(float4*)&ho[8];
  *(float4*)&Eb[ebase + 12] = *(float4*)&ho[12];
}

// ---------------- scan pass 1: full recurrence from h_in (in Eb) ----------------
// ATOMIC=0: store y into per-direction plane ybuf[(bk,p,d)]. ATOMIC=1: legacy atomicAdd.
template <int T, int ATOMIC>
__global__ __launch_bounds__(384) void k_scan1(
    const float* __restrict__ dtsS, const float* __restrict__ BsS,
    const float* __restrict__ CsS, const __hip_bfloat16* __restrict__ xcb,
    const float* __restrict__ A_logs, const float* __restrict__ dt_w,
    const float* __restrict__ dt_b, const float* __restrict__ Eb,
    float* __restrict__ yout) {
  constexpr int SEG = 4096 / T;
  int bid = blockIdx.x;
  int s = bid & (SEG - 1), bk = bid / SEG;
  int k = bk & 3, b = bk >> 2;
  int d = threadIdx.x;
  float w[12];
  const float* dwp = dt_w + ((long)(k * 384) + d) * 12;
  #pragma unroll
  for (int r = 0; r < 12; r++) w[r] = dwp[r];
  float db = dt_b[k * 384 + d];
  const float* al = A_logs + ((long)(k * 384) + d) * 16;
  bool pw = true;
  float av[16];
  #pragma unroll
  for (int n = 0; n < 16; n++) {
    float a = __expf(al[n]);
    av[n] = -a;
    pw = pw && (fabsf(a - (float)(n + 1)) < 1e-3f);
  }
  float h[16];
  const float* hp = Eb + ((long)bk * SEG + s) * 6144 + d * 16;
  #pragma unroll
  for (int n = 0; n < 16; n++) h[n] = hp[n];
  long bpk = (long)bk << 12;
  long bpix = (long)(b << 12);

  if (pw) {
    #pragma unroll 4
    for (int t = 0; t < T; t++) {
      int p = dir_pix(k, s * T + t);
      const float4* dq = (const float4*)(dtsS + (bpk + p) * 12);
      float4 q0 = dq[0], q1 = dq[1], q2 = dq[2];
      float x = db + q0.x * w[0] + q0.y * w[1] + q0.z * w[2] + q0.w * w[3]
                   + q1.x * w[4] + q1.y * w[5] + q1.z * w[6] + q1.w * w[7]
                   + q2.x * w[8] + q2.y * w[9] + q2.z * w[10] + q2.w * w[11];
      float e = __expf(x);
      float delta = (x > 15.f) ? x : __logf(1.f + e);
      float u = __bfloat162float(xcb[(bpix + p) * 384 + d]);
      float du = delta * u;
      float rr = __builtin_amdgcn_rcpf(1.f + e);
      float pws[16]; pow16(rr, pws);
      const float4* Bq = (const float4*)(BsS + (bpk + p) * 16);
      float4 b0 = Bq[0], b1 = Bq[1], b2 = Bq[2], b3 = Bq[3];
      float Bl[16] = {b0.x, b0.y, b0.z, b0.w, b1.x, b1.y, b1.z, b1.w,
                      b2.x, b2.y, b2.z, b2.w, b3.x, b3.y, b3.z, b3.w};
      const float4* Cq = (const float4*)(CsS + (bpk + p) * 16);
      float4 c0 = Cq[0], c1 = Cq[1], c2 = Cq[2], c3 = Cq[3];
      float Cl[16] = {c0.x, c0.y, c0.z, c0.w, c1.x, c1.y, c1.z, c1.w,
                      c2.x, c2.y, c2.z, c2.w, c3.x, c3.y, c3.z, c3.w};
      float y = 0.f;
      #pragma unroll
      for (int n = 0; n < 16; n++) { h[n] = pws[n] * h[n] + du * Bl[n]; y += h[n] * Cl[n]; }
      if (ATOMIC) atomicAdd(&yout[(bpix + p) * 384 + d], y);
      else        yout[(bpk + p) * 384 + d] = y;
    }
  } else {
    for (int t = 0; t < T; t++) {
      int p = dir_pix(k, s * T + t);
      const float4* dq = (const float4*)(dtsS + (bpk + p) * 12);
      float4 q0 = dq[0], q1 = dq[1], q2 = dq[2];
      float x = db + q0.x * w[0] + q0.y * w[1] + q0.z * w[2] + q0.w * w[3]
                   + q1.x * w[4] + q1.y * w[5] + q1.z * w[6] + q1.w * w[7]
                   + q2.x * w[8] + q2.y * w[9] + q2.z * w[10] + q2.w * w[11];
      float e = __expf(x);
      float delta = (x > 15.f) ? x : __logf(1.f + e);
      float u = __bfloat162float(xcb[(bpix + p) * 384 + d]);
      float du = delta * u;
      const float4* Bq = (const float4*)(BsS + (bpk + p) * 16);
      float4 b0 = Bq[0], b1 = Bq[1], b2 = Bq[2], b3 = Bq[3];
      float Bl[16] = {b0.x, b0.y, b0.z, b0.w, b1.x, b1.y, b1.z, b1.w,
                      b2.x, b2.y, b2.z, b2.w, b3.x, b3.y, b3.z, b3.w};
      const float4* Cq = (const float4*)(CsS + (bpk + p) * 16);
      float4 c0 = Cq[0], c1 = Cq[1], c2 = Cq[2], c3 = Cq[3];
      float Cl[16] = {c0.x, c0.y, c0.z, c0.w, c1.x, c1.y, c1.z, c1.w,
                      c2.x, c2.y, c2.z, c2.w, c3.x, c3.y, c3.z, c3.w};
      float y = 0.f;
      #pragma unroll
      for (int n = 0; n < 16; n++) {
        float dA = __expf(delta * av[n]);
        h[n] = dA * h[n] + du * Bl[n];
        y += h[n] * Cl[n];
      }
      if (ATOMIC) atomicAdd(&yout[(bpix + p) * 384 + d], y);
      else        yout[(bpk + p) * 384 + d] = y;
    }
  }
}

// ---------------- merge: y + D-skip(bf16 xcb) + out-LN + silu(z bf16) -> bf16 ----------------
template <int GATHER>
__global__ __launch_bounds__(384) void k_merge(const float* __restrict__ yin,
                                               const __hip_bfloat16* __restrict__ xcb,
                                               const __hip_bfloat16* __restrict__ zbufB,
                                               const float* __restrict__ Ds,
                                               const float* __restrict__ g,
                                               const float* __restrict__ be,
                                               __hip_bfloat16* __restrict__ yactb) {
  int row = blockIdx.x;
  int d = threadIdx.x;
  float v;
  if (GATHER) {
    int b = row >> 12, p = row & 4095;
    long base = ((long)(b << 2) << 12) + p;  // plane (b*4+k)*4096 + p
    v = yin[base * 384 + d]
      + yin[(base + 4096) * 384 + d]
      + yin[(base + 8192) * 384 + d]
      + yin[(base + 12288) * 384 + d];
  } else {
    v = yin[(long)row * 384 + d];
  }
  float sd = Ds[d] + Ds[384 + d] + Ds[768 + d] + Ds[1152 + d];
  v += __bfloat162float(xcb[(long)row * 384 + d]) * sd;
  float s1 = v, s2 = v * v;
  #pragma unroll
  for (int o = 32; o > 0; o >>= 1) { s1 += __shfl_xor(s1, o); s2 += __shfl_xor(s2, o); }
  __shared__ float r1[6], r2[6];
  int wv = threadIdx.x >> 6;
  if ((threadIdx.x & 63) == 0) { r1[wv] = s1; r2[wv] = s2; }
  __syncthreads();
  float S1 = 0.f, S2 = 0.f;
  #pragma unroll
  for (int i = 0; i < 6; i++) { S1 += r1[i]; S2 += r2[i]; }
  float mu = S1 * (1.f / 384.f);
  float var = S2 * (1.f / 384.f) - mu * mu;
  float rr = rsqrtf(var + 1e-5f);
  float yn = (v - mu) * rr * g[d] + be[d];
  float z = __bfloat162float(zbufB[(long)row * 384 + d]);
  float sg = z / (1.f + __expf(-z));
  yactb[(long)row * 384 + d] = __float2bfloat16(yn * sg);
}

extern "C" void kernel_launch(void* const* d_in, const int* in_sizes, int n_in,
                              void* d_out, int out_size, void* d_ws, size_t ws_size,
                              hipStream_t stream) {
  const float* input      = (const float*)d_in[0];
  const float* norm_g     = (const float*)d_in[1];
  const float* norm_b     = (const float*)d_in[2];
  const float* in_proj_w  = (const float*)d_in[3];
  const float* conv_w     = (const float*)d_in[4];
  const float* conv_b     = (const float*)d_in[5];
  const float* x_proj_w   = (const float*)d_in[6];
  const float* dt_w       = (const float*)d_in[7];
  const float* dt_b       = (const float*)d_in[8];
  const float* A_logs     = (const float*)d_in[9];
  const float* Ds         = (const float*)d_in[10];
  const float* out_norm_g = (const float*)d_in[11];
  const float* out_norm_b = (const float*)d_in[12];
  const float* out_proj_w = (const float*)d_in[13];
  float* out = (float*)d_out;

  // which scan config fits the workspace?
  // S=256 path total = 34,619,392 floats (~138 MB); S=128 planes = 27,934,720 (~112 MB);
  // S=128 atomic = 18,497,536 (~74 MB)
  bool big2 = ws_size >= (size_t)34619392 * 4;
  bool big  = ws_size >= (size_t)27934720 * 4;
  int SEG = big2 ? 256 : 128;

  float* ws = (float*)d_ws;
  long o = 0;
  __hip_bfloat16* xnb   = (__hip_bfloat16*)(ws + o); o += 786432;   // 8192x192 bf16
  __hip_bfloat16* xbufB = (__hip_bfloat16*)(ws + o); o += 1572864;  // 8192x384 bf16
  __hip_bfloat16* zbufB = (__hip_bfloat16*)(ws + o); o += 1572864;
  __hip_bfloat16* xcb   = (__hip_bfloat16*)(ws + o); o += 1572864;
  __hip_bfloat16* Wt1   = (__hip_bfloat16*)(ws + o); o += 73728;    // 768x192 bf16
  __hip_bfloat16* Wt2   = (__hip_bfloat16*)(ws + o); o += 36864;
  __hip_bfloat16* Wt3   = (__hip_bfloat16*)(ws + o); o += 36864;
  float* dtsS           = ws + o;                    o += 393216;   // (BK,p,12) pixel order
  float* BsS            = ws + o;                    o += 524288;   // (BK,p,16)
  float* CsS            = ws + o;                    o += 524288;
  float* Eb             = ws + o;                    o += (long)8 * SEG * 6144;  // E then h_in
  float* Dend           = ws + o;                    o += (long)8 * SEG * 384;
  float* ybuf           = ws + o;                    o += big ? 12582912 : 3145728;
  __hip_bfloat16* yactb = (__hip_bfloat16*)(ws + o); o += 1572864;

  k_ln<<<dim3(2048), dim3(256), 0, stream>>>(input, norm_g, norm_b, xnb);
  k_packw<<<dim3(1152), dim3(256), 0, stream>>>(in_proj_w, x_proj_w, out_proj_w, Wt1, Wt2, Wt3);
  k_gemm_mfma<2><<<dim3(12, 128), dim3(256), 0, stream>>>(xnb, Wt1, nullptr, nullptr, xbufB, zbufB,
                                                          nullptr, nullptr, nullptr, 8192, 768, 192);
  k_conv<<<dim3(8192), dim3(384), 0, stream>>>(xbufB, conv_w, conv_b, xcb);
  k_gemm_mfma<3><<<dim3(3, 128), dim3(256), 0, stream>>>(xcb, Wt2, nullptr, nullptr, nullptr, nullptr,
                                                         dtsS, BsS, CsS, 8192, 192, 384);
  if (big2) {
    k_scan0<16><<<dim3(2048), dim3(384), 0, stream>>>(dtsS, BsS, xcb, A_logs, dt_w, dt_b, Eb, Dend);
    k_combine<256><<<dim3(3072), dim3(256), 0, stream>>>(Eb, Dend, A_logs);
    k_scan1<16, 0><<<dim3(2048), dim3(384), 0, stream>>>(dtsS, BsS, CsS, xcb, A_logs, dt_w, dt_b, Eb, ybuf);
    k_merge<1><<<dim3(8192), dim3(384), 0, stream>>>(ybuf, xcb, zbufB, Ds, out_norm_g, out_norm_b, yactb);
  } else if (big) {
    k_scan0<32><<<dim3(1024), dim3(384), 0, stream>>>(dtsS, BsS, xcb, A_logs, dt_w, dt_b, Eb, Dend);
    k_combine<128><<<dim3(3072), dim3(128), 0, stream>>>(Eb, Dend, A_logs);
    k_scan1<32, 0><<<dim3(1024), dim3(384), 0, stream>>>(dtsS, BsS, CsS, xcb, A_logs, dt_w, dt_b, Eb, ybuf);
    k_merge<1><<<dim3(8192), dim3(384), 0, stream>>>(ybuf, xcb, zbufB, Ds, out_norm_g, out_norm_b, yactb);
  } else {
    k_scan0<32><<<dim3(1024), dim3(384), 0, stream>>>(dtsS, BsS, xcb, A_logs, dt_w, dt_b, Eb, Dend);
    k_combine<128><<<dim3(3072), dim3(128), 0, stream>>>(Eb, Dend, A_logs);
    hipMemsetAsync(ybuf, 0, (size_t)3145728 * 4, stream);
    k_scan1<32, 1><<<dim3(1024), dim3(384), 0, stream>>>(dtsS, BsS, CsS, xcb, A_logs, dt_w, dt_b, Eb, ybuf);
    k_merge<0><<<dim3(8192), dim3(384), 0, stream>>>(ybuf, xcb, zbufB, Ds, out_norm_g, out_norm_b, yactb);
  }
  k_gemm_mfma<1><<<dim3(3, 128), dim3(256), 0, stream>>>(yactb, Wt3, input, out, nullptr, nullptr,
                                                         nullptr, nullptr, nullptr, 8192, 192, 384);
}

// Round 4
// 261.634 us; speedup vs baseline: 1.1106x; 1.1106x over previous
//
#include <hip/hip_runtime.h>
#include <hip/hip_bf16.h>
#include <hip/hip_fp16.h>

// VSSBlock: B=2 H=64 W=64 C=192 DM=384 N=16 R=12 K=4 L=4096
// R12: back to R9 scan structure (T=32/SEG=128, broadcast VMEM — best measured).
//      ONE change: k_dt precomputes delta=softplus(dts@dt_w+dt_b) as fp16 plane once;
//      both scans drop the 12-FMA dot + softplus (+2 trans) per step and load delta
//      coalesced instead. Combine keeps pow16 fast path.

typedef __attribute__((ext_vector_type(8))) short short8;     // 8 bf16 = 4 VGPRs
typedef __attribute__((ext_vector_type(4))) float floatx4;    // fp32 accum frag

// ---------------- LayerNorm (pre-norm, eps 1e-6), C=192 -> bf16 ----------------
__global__ __launch_bounds__(256) void k_ln(const float* __restrict__ in,
                                            const float* __restrict__ g,
                                            const float* __restrict__ be,
                                            __hip_bfloat16* __restrict__ out) {
  int row = blockIdx.x * 4 + (threadIdx.x >> 6);
  int lane = threadIdx.x & 63;
  const float* x = in + (long)row * 192;
  float v0 = x[lane], v1 = x[lane + 64], v2 = x[lane + 128];
  float s = v0 + v1 + v2;
  float s2 = v0 * v0 + v1 * v1 + v2 * v2;
  #pragma unroll
  for (int o = 32; o > 0; o >>= 1) { s += __shfl_xor(s, o); s2 += __shfl_xor(s2, o); }
  float mu = s * (1.f / 192.f);
  float var = s2 * (1.f / 192.f) - mu * mu;
  float r = rsqrtf(var + 1e-6f);
  __hip_bfloat16* op = out + (long)row * 192;
  op[lane]       = __float2bfloat16((v0 - mu) * r * g[lane]       + be[lane]);
  op[lane + 64]  = __float2bfloat16((v1 - mu) * r * g[lane + 64]  + be[lane + 64]);
  op[lane + 128] = __float2bfloat16((v2 - mu) * r * g[lane + 128] + be[lane + 128]);
}

// ---------------- pack weights -> bf16, transposed to (N x K) ----------------
__global__ __launch_bounds__(256) void k_packw(const float* __restrict__ ipw,
                                               const float* __restrict__ xpw,
                                               const float* __restrict__ opw,
                                               __hip_bfloat16* __restrict__ Wt1,
                                               __hip_bfloat16* __restrict__ Wt2,
                                               __hip_bfloat16* __restrict__ Wt3) {
  int idx = blockIdx.x * 256 + threadIdx.x;
  if (idx < 147456) {                       // Wt1[n][k] = ipw[k][n]
    int n = idx / 192, k = idx - n * 192;
    Wt1[idx] = __float2bfloat16(ipw[(long)k * 768 + n]);
  } else if (idx < 147456 + 73728) {        // Wt2[j][d]
    int t = idx - 147456;
    int j = t / 384;
    float v = (j < 176) ? xpw[t] : 0.f;
    Wt2[t] = __float2bfloat16(v);
  } else if (idx < 147456 + 73728 + 73728) {// Wt3[n][k] = opw[k][n]
    int t = idx - 147456 - 73728;
    int n = t / 384, k = t - n * 384;
    Wt3[t] = __float2bfloat16(opw[(long)k * 192 + n]);
  }
}

// direction map (involutions): pixel p <-> scan position l
__device__ __forceinline__ int inv_dir(int k, int p) {
  int pt = ((p & 63) << 6) | (p >> 6);
  if (k == 0) return p;
  if (k == 1) return pt;
  if (k == 2) return 4095 - p;
  return 4095 - pt;
}
__device__ __forceinline__ int dir_pix(int k, int l) { return inv_dir(k, l); }

// ---------------- bf16 MFMA GEMM: 64x64 tile, BK=64, XOR-swizzled LDS ----------------
template <int EPI>
__global__ __launch_bounds__(256) void k_gemm_mfma(const __hip_bfloat16* __restrict__ A,
                                                   const __hip_bfloat16* __restrict__ Bt,
                                                   const float* __restrict__ Res,
                                                   float* __restrict__ Co,
                                                   __hip_bfloat16* __restrict__ CoB,
                                                   __hip_bfloat16* __restrict__ Co2B,
                                                   float* __restrict__ dtsS,
                                                   float* __restrict__ BsS,
                                                   float* __restrict__ CsS,
                                                   int M, int N, int Kk) {
  __shared__ __align__(16) short As[64 * 64];
  __shared__ __align__(16) short Bs[64 * 64];
  int tid = threadIdx.x;
  int wave = tid >> 6, lane = tid & 63;
  int mlane = lane & 15, quad = lane >> 4;
  int row0 = blockIdx.y * 64, col0 = blockIdx.x * 64;
  int wr = wave & 1, wc = wave >> 1;
  floatx4 acc[2][2];
  #pragma unroll
  for (int mi = 0; mi < 2; mi++)
    #pragma unroll
    for (int ni = 0; ni < 2; ni++) acc[mi][ni] = (floatx4){0.f, 0.f, 0.f, 0.f};

  for (int k0 = 0; k0 < Kk; k0 += 64) {
    #pragma unroll
    for (int c = tid; c < 512; c += 256) {
      int r = c >> 3, j = c & 7;
      *(float4*)&As[r * 64 + ((j ^ (r & 7)) << 3)] =
          *(const float4*)&A[(long)(row0 + r) * Kk + k0 + j * 8];
    }
    #pragma unroll
    for (int c = tid; c < 512; c += 256) {
      int r = c >> 3, j = c & 7;
      *(float4*)&Bs[r * 64 + ((j ^ (r & 7)) << 3)] =
          *(const float4*)&Bt[(long)(col0 + r) * Kk + k0 + j * 8];
    }
    __syncthreads();
    short8 af[2][2], bf[2][2];
    #pragma unroll
    for (int mi = 0; mi < 2; mi++) {
      int r = wr * 32 + mi * 16 + mlane;
      #pragma unroll
      for (int kk = 0; kk < 2; kk++) {
        int jx = (kk * 4 + quad) ^ (r & 7);
        af[mi][kk] = *(const short8*)&As[r * 64 + jx * 8];
      }
    }
    #pragma unroll
    for (int ni = 0; ni < 2; ni++) {
      int rn = wc * 32 + ni * 16 + mlane;
      #pragma unroll
      for (int kk = 0; kk < 2; kk++) {
        int jx = (kk * 4 + quad) ^ (rn & 7);
        bf[ni][kk] = *(const short8*)&Bs[rn * 64 + jx * 8];
      }
    }
    #pragma unroll
    for (int kk = 0; kk < 2; kk++)
      #pragma unroll
      for (int mi = 0; mi < 2; mi++)
        #pragma unroll
        for (int ni = 0; ni < 2; ni++)
          acc[mi][ni] = __builtin_amdgcn_mfma_f32_16x16x32_bf16(af[mi][kk], bf[ni][kk],
                                                                acc[mi][ni], 0, 0, 0);
    __syncthreads();
  }
  // C/D layout: col=lane&15, row=quad*4+reg  [m89-verified]
  #pragma unroll
  for (int mi = 0; mi < 2; mi++) {
    #pragma unroll
    for (int ni = 0; ni < 2; ni++) {
      int cc = col0 + wc * 32 + ni * 16 + mlane;
      #pragma unroll
      for (int i = 0; i < 4; i++) {
        int rr = row0 + wr * 32 + mi * 16 + quad * 4 + i;
        float v = acc[mi][ni][i];
        if (EPI == 1) {
          Co[(long)rr * N + cc] = v + Res[(long)rr * N + cc];
        } else if (EPI == 2) {
          if (cc < 384) CoB[(long)rr * 384 + cc] = __float2bfloat16(v);
          else          Co2B[(long)rr * 384 + (cc - 384)] = __float2bfloat16(v);
        } else {  // EPI == 3: pixel-order x_dbl split -> coalesced stores
          if (cc < 176) {
            int k4 = (cc >= 132) ? 3 : (cc >= 88) ? 2 : (cc >= 44) ? 1 : 0;
            int c = cc - k4 * 44;
            int b = rr >> 12, p = rr & 4095;
            long lbase = ((long)((b << 2) + k4) << 12) + p;   // pixel order
            if (c < 12)      dtsS[lbase * 12 + c] = v;
            else if (c < 28) BsS[lbase * 16 + (c - 12)] = v;
            else             CsS[lbase * 16 + (c - 28)] = v;
          }
        }
      }
    }
  }
}

// ---------------- depthwise 3x3 conv + bias + SiLU; bf16 in, bf16 out ----------------
__global__ __launch_bounds__(384) void k_conv(const __hip_bfloat16* __restrict__ xbufB,
                                              const float* __restrict__ cw,
                                              const float* __restrict__ cb,
                                              __hip_bfloat16* __restrict__ xcb) {
  int row = blockIdx.x;
  int b = row >> 12, p = row & 4095;
  int h = p >> 6, w0 = p & 63;
  int d = threadIdx.x;
  float acc = cb[d];
  const float* wt = cw + d * 9;
  #pragma unroll
  for (int dh = -1; dh <= 1; dh++) {
    int hh = h + dh;
    if (hh < 0 || hh > 63) continue;
    #pragma unroll
    for (int dw = -1; dw <= 1; dw++) {
      int ww = w0 + dw;
      if (ww < 0 || ww > 63) continue;
      acc += __bfloat162float(xbufB[((long)(b << 12) + (hh << 6) + ww) * 384 + d])
             * wt[(dh + 1) * 3 + (dw + 1)];
    }
  }
  float sg = 1.f / (1.f + __expf(-acc));
  xcb[(long)row * 384 + d] = __float2bfloat16(acc * sg);
}

// ---------------- dt precompute: delta = softplus(dts @ dt_w^T + dt_b) -> fp16 plane ----------------
// grid: (bk, 128 chunks of 32 pixels); 384 threads (one per d). w[] in regs, dts broadcast.
__global__ __launch_bounds__(384) void k_dt(const float* __restrict__ dtsS,
                                            const float* __restrict__ dt_w,
                                            const float* __restrict__ dt_b,
                                            __half* __restrict__ dpre) {
  int bid = blockIdx.x;
  int chunk = bid & 127, bk = bid >> 7;
  int k = bk & 3;
  int d = threadIdx.x;
  float w[12];
  const float* dwp = dt_w + ((long)(k * 384) + d) * 12;
  #pragma unroll
  for (int r = 0; r < 12; r++) w[r] = dwp[r];
  float db = dt_b[k * 384 + d];
  long base = ((long)bk << 12) + chunk * 32;
  #pragma unroll 4
  for (int t = 0; t < 32; t++) {
    const float4* dq = (const float4*)(dtsS + (base + t) * 12);
    float4 q0 = dq[0], q1 = dq[1], q2 = dq[2];
    float x = db + q0.x * w[0] + q0.y * w[1] + q0.z * w[2] + q0.w * w[3]
                 + q1.x * w[4] + q1.y * w[5] + q1.z * w[6] + q1.w * w[7]
                 + q2.x * w[8] + q2.y * w[9] + q2.z * w[10] + q2.w * w[11];
    float e = __expf(x);
    float delta = (x > 15.f) ? x : __logf(1.f + e);
    dpre[(base + t) * 384 + d] = __float2half(delta);
  }
}

// powers: pws[n] = r^(n+1), log-depth pairing
__device__ __forceinline__ void pow16(float r, float* pws) {
  pws[0] = r;
  #pragma unroll
  for (int n = 1; n < 16; n++) {
    int m = n + 1, c = (m + 1) / 2, f = m - c;
    pws[n] = pws[c - 1] * pws[f - 1];
  }
}

// ---------------- scan pass 0: 128 segments x 32 steps; E[16] + scalar cumDelta ----------------
__global__ __launch_bounds__(384) void k_scan0(
    const __half* __restrict__ dpre, const float* __restrict__ BsS,
    const __hip_bfloat16* __restrict__ xcb,
    const float* __restrict__ A_logs,
    float* __restrict__ Eb, float* __restrict__ Dend) {
  int bid = blockIdx.x;
  int s = bid & 127, bk = bid >> 7;
  int k = bk & 3, b = bk >> 2;
  int d = threadIdx.x;
  const float* al = A_logs + ((long)(k * 384) + d) * 16;
  bool pw = true;
  float av[16];
  #pragma unroll
  for (int n = 0; n < 16; n++) {
    float a = __expf(al[n]);
    av[n] = -a;
    pw = pw && (fabsf(a - (float)(n + 1)) < 1e-3f);
  }
  float h[16];
  #pragma unroll
  for (int n = 0; n < 16; n++) h[n] = 0.f;
  float cum = 0.f;
  long bpk = (long)bk << 12;
  long bpix = (long)(b << 12);

  if (pw) {
    #pragma unroll 4
    for (int t = 0; t < 32; t++) {
      int p = dir_pix(k, s * 32 + t);
      float delta = __half2float(dpre[(bpk + p) * 384 + d]);
      cum += delta;
      float u = __bfloat162float(xcb[(bpix + p) * 384 + d]);
      float du = delta * u;
      float rr = __expf(-delta);
      float pws[16]; pow16(rr, pws);
      const float4* Bq = (const float4*)(BsS + (bpk + p) * 16);
      float4 b0 = Bq[0], b1 = Bq[1], b2 = Bq[2], b3 = Bq[3];
      float Bl[16] = {b0.x, b0.y, b0.z, b0.w, b1.x, b1.y, b1.z, b1.w,
                      b2.x, b2.y, b2.z, b2.w, b3.x, b3.y, b3.z, b3.w};
      #pragma unroll
      for (int n = 0; n < 16; n++) h[n] = pws[n] * h[n] + du * Bl[n];
    }
  } else {
    for (int t = 0; t < 32; t++) {
      int p = dir_pix(k, s * 32 + t);
      float delta = __half2float(dpre[(bpk + p) * 384 + d]);
      cum += delta;
      float u = __bfloat162float(xcb[(bpix + p) * 384 + d]);
      float du = delta * u;
      const float4* Bq = (const float4*)(BsS + (bpk + p) * 16);
      float4 b0 = Bq[0], b1 = Bq[1], b2 = Bq[2], b3 = Bq[3];
      float Bl[16] = {b0.x, b0.y, b0.z, b0.w, b1.x, b1.y, b1.z, b1.w,
                      b2.x, b2.y, b2.z, b2.w, b3.x, b3.y, b3.z, b3.w};
      #pragma unroll
      for (int n = 0; n < 16; n++) {
        float dA = __expf(delta * av[n]);
        h[n] = dA * h[n] + du * Bl[n];
      }
    }
  }
  long g = (long)bk * 128 + s;
  float* Ep = Eb + g * 6144 + d * 16;
  #pragma unroll
  for (int n = 0; n < 16; n++) Ep[n] = h[n];
  Dend[g * 384 + d] = cum;
}

// ---------------- combine: Kogge-Stone over 128 segments; pow16 trick ----------------
__global__ __launch_bounds__(128) void k_combine(float* __restrict__ Eb,
                                                 const float* __restrict__ Dend,
                                                 const float* __restrict__ A_logs) {
  int bid = blockIdx.x;            // bk*384 + d, 3072 blocks
  int bk = bid / 384;
  int d = bid - bk * 384;
  int k = bk & 3;
  int s = threadIdx.x;             // segment 0..127
  const float* al = A_logs + ((long)(k * 384) + d) * 16;
  bool pw = true;
  float av[16];
  #pragma unroll
  for (int n = 0; n < 16; n++) {
    float a = __expf(al[n]);
    av[n] = -a;
    pw = pw && (fabsf(a - (float)(n + 1)) < 1e-3f);
  }

  long ebase = ((long)bk * 128 + s) * 6144 + d * 16;
  float e[16];
  *(float4*)&e[0]  = *(const float4*)&Eb[ebase + 0];
  *(float4*)&e[4]  = *(const float4*)&Eb[ebase + 4];
  *(float4*)&e[8]  = *(const float4*)&Eb[ebase + 8];
  *(float4*)&e[12] = *(const float4*)&Eb[ebase + 12];
  float sig = Dend[((long)bk * 128 + s) * 384 + d];

  __shared__ float sE[128][17];    // [s][0]=sigma, [s][1..16]=e
  sE[s][0] = sig;
  #pragma unroll
  for (int n = 0; n < 16; n++) sE[s][1 + n] = e[n];
  __syncthreads();

  for (int o = 1; o < 128; o <<= 1) {
    float ps = 0.f, pe[16];
    bool act = (s >= o);
    if (act) {
      ps = sE[s - o][0];
      #pragma unroll
      for (int n = 0; n < 16; n++) pe[n] = sE[s - o][1 + n];
    }
    __syncthreads();
    if (act) {
      if (pw) {
        float rc = __expf(-sig);
        float pwr[16]; pow16(rc, pwr);      // pwr[n] = exp(av[n]*sig), av[n]=-(n+1)
        #pragma unroll
        for (int n = 0; n < 16; n++) e[n] += pwr[n] * pe[n];
      } else {
        #pragma unroll
        for (int n = 0; n < 16; n++) e[n] += __expf(av[n] * sig) * pe[n];
      }
      sig += ps;
      sE[s][0] = sig;
      #pragma unroll
      for (int n = 0; n < 16; n++) sE[s][1 + n] = e[n];
    }
    __syncthreads();
  }

  float ho[16];
  if (s == 0) {
    #pragma unroll
    for (int n = 0; n < 16; n++) ho[n] = 0.f;
  } else {
    #pragma unroll
    for (int n = 0; n < 16; n++) ho[n] = sE[s - 1][1 + n];
  }
  *(float4*)&Eb[ebase + 0]  = *(float4*)&ho[0];
  *(float4*)&Eb[ebase + 4]  = *(float4*)&ho[4];
  *(float4*)&Eb[ebase + 8]  = *(float4*)&ho[8];
  *(float4*)&Eb[ebase + 12] = *(float4*)&ho[12];
}

// ---------------- scan pass 1: full recurrence from h_in (in Eb) ----------------
// ATOMIC=0: store y into per-direction plane ybuf[(bk,p,d)]. ATOMIC=1: legacy atomicAdd.
template <int ATOMIC>
__global__ __launch_bounds__(384) void k_scan1(
    const __half* __restrict__ dpre, const float* __restrict__ BsS,
    const float* __restrict__ CsS, const __hip_bfloat16* __restrict__ xcb,
    const float* __restrict__ A_logs, const float* __restrict__ Eb,
    float* __restrict__ yout) {
  int bid = blockIdx.x;
  int s = bid & 127, bk = bid >> 7;
  int k = bk & 3, b = bk >> 2;
  int d = threadIdx.x;
  const float* al = A_logs + ((long)(k * 384) + d) * 16;
  bool pw = true;
  float av[16];
  #pragma unroll
  for (int n = 0; n < 16; n++) {
    float a = __expf(al[n]);
    av[n] = -a;
    pw = pw && (fabsf(a - (float)(n + 1)) < 1e-3f);
  }
  float h[16];
  const float* hp = Eb + ((long)bk * 128 + s) * 6144 + d * 16;
  #pragma unroll
  for (int n = 0; n < 16; n++) h[n] = hp[n];
  long bpk = (long)bk << 12;
  long bpix = (long)(b << 12);

  if (pw) {
    #pragma unroll 4
    for (int t = 0; t < 32; t++) {
      int p = dir_pix(k, s * 32 + t);
      float delta = __half2float(dpre[(bpk + p) * 384 + d]);
      float u = __bfloat162float(xcb[(bpix + p) * 384 + d]);
      float du = delta * u;
      float rr = __expf(-delta);
      float pws[16]; pow16(rr, pws);
      const float4* Bq = (const float4*)(BsS + (bpk + p) * 16);
      float4 b0 = Bq[0], b1 = Bq[1], b2 = Bq[2], b3 = Bq[3];
      float Bl[16] = {b0.x, b0.y, b0.z, b0.w, b1.x, b1.y, b1.z, b1.w,
                      b2.x, b2.y, b2.z, b2.w, b3.x, b3.y, b3.z, b3.w};
      const float4* Cq = (const float4*)(CsS + (bpk + p) * 16);
      float4 c0 = Cq[0], c1 = Cq[1], c2 = Cq[2], c3 = Cq[3];
      float Cl[16] = {c0.x, c0.y, c0.z, c0.w, c1.x, c1.y, c1.z, c1.w,
                      c2.x, c2.y, c2.z, c2.w, c3.x, c3.y, c3.z, c3.w};
      float y = 0.f;
      #pragma unroll
      for (int n = 0; n < 16; n++) { h[n] = pws[n] * h[n] + du * Bl[n]; y += h[n] * Cl[n]; }
      if (ATOMIC) atomicAdd(&yout[(bpix + p) * 384 + d], y);
      else        yout[(bpk + p) * 384 + d] = y;
    }
  } else {
    for (int t = 0; t < 32; t++) {
      int p = dir_pix(k, s * 32 + t);
      float delta = __half2float(dpre[(bpk + p) * 384 + d]);
      float u = __bfloat162float(xcb[(bpix + p) * 384 + d]);
      float du = delta * u;
      const float4* Bq = (const float4*)(BsS + (bpk + p) * 16);
      float4 b0 = Bq[0], b1 = Bq[1], b2 = Bq[2], b3 = Bq[3];
      float Bl[16] = {b0.x, b0.y, b0.z, b0.w, b1.x, b1.y, b1.z, b1.w,
                      b2.x, b2.y, b2.z, b2.w, b3.x, b3.y, b3.z, b3.w};
      const float4* Cq = (const float4*)(CsS + (bpk + p) * 16);
      float4 c0 = Cq[0], c1 = Cq[1], c2 = Cq[2], c3 = Cq[3];
      float Cl[16] = {c0.x, c0.y, c0.z, c0.w, c1.x, c1.y, c1.z, c1.w,
                      c2.x, c2.y, c2.z, c2.w, c3.x, c3.y, c3.z, c3.w};
      float y = 0.f;
      #pragma unroll
      for (int n = 0; n < 16; n++) {
        float dA = __expf(delta * av[n]);
        h[n] = dA * h[n] + du * Bl[n];
        y += h[n] * Cl[n];
      }
      if (ATOMIC) atomicAdd(&yout[(bpix + p) * 384 + d], y);
      else        yout[(bpk + p) * 384 + d] = y;
    }
  }
}

// ---------------- merge: y + D-skip(bf16 xcb) + out-LN + silu(z bf16) -> bf16 ----------------
template <int GATHER>
__global__ __launch_bounds__(384) void k_merge(const float* __restrict__ yin,
                                               const __hip_bfloat16* __restrict__ xcb,
                                               const __hip_bfloat16* __restrict__ zbufB,
                                               const float* __restrict__ Ds,
                                               const float* __restrict__ g,
                                               const float* __restrict__ be,
                                               __hip_bfloat16* __restrict__ yactb) {
  int row = blockIdx.x;
  int d = threadIdx.x;
  float v;
  if (GATHER) {
    int b = row >> 12, p = row & 4095;
    long base = ((long)(b << 2) << 12) + p;  // plane (b*4+k)*4096 + p
    v = yin[base * 384 + d]
      + yin[(base + 4096) * 384 + d]
      + yin[(base + 8192) * 384 + d]
      + yin[(base + 12288) * 384 + d];
  } else {
    v = yin[(long)row * 384 + d];
  }
  float sd = Ds[d] + Ds[384 + d] + Ds[768 + d] + Ds[1152 + d];
  v += __bfloat162float(xcb[(long)row * 384 + d]) * sd;
  float s1 = v, s2 = v * v;
  #pragma unroll
  for (int o = 32; o > 0; o >>= 1) { s1 += __shfl_xor(s1, o); s2 += __shfl_xor(s2, o); }
  __shared__ float r1[6], r2[6];
  int wv = threadIdx.x >> 6;
  if ((threadIdx.x & 63) == 0) { r1[wv] = s1; r2[wv] = s2; }
  __syncthreads();
  float S1 = 0.f, S2 = 0.f;
  #pragma unroll
  for (int i = 0; i < 6; i++) { S1 += r1[i]; S2 += r2[i]; }
  float mu = S1 * (1.f / 384.f);
  float var = S2 * (1.f / 384.f) - mu * mu;
  float rr = rsqrtf(var + 1e-5f);
  float yn = (v - mu) * rr * g[d] + be[d];
  float z = __bfloat162float(zbufB[(long)row * 384 + d]);
  float sg = z / (1.f + __expf(-z));
  yactb[(long)row * 384 + d] = __float2bfloat16(yn * sg);
}

extern "C" void kernel_launch(void* const* d_in, const int* in_sizes, int n_in,
                              void* d_out, int out_size, void* d_ws, size_t ws_size,
                              hipStream_t stream) {
  const float* input      = (const float*)d_in[0];
  const float* norm_g     = (const float*)d_in[1];
  const float* norm_b     = (const float*)d_in[2];
  const float* in_proj_w  = (const float*)d_in[3];
  const float* conv_w     = (const float*)d_in[4];
  const float* conv_b     = (const float*)d_in[5];
  const float* x_proj_w   = (const float*)d_in[6];
  const float* dt_w       = (const float*)d_in[7];
  const float* dt_b       = (const float*)d_in[8];
  const float* A_logs     = (const float*)d_in[9];
  const float* Ds         = (const float*)d_in[10];
  const float* out_norm_g = (const float*)d_in[11];
  const float* out_norm_b = (const float*)d_in[12];
  const float* out_proj_w = (const float*)d_in[13];
  float* out = (float*)d_out;

  // plane path total = 34,226,176 floats (~137 MB); atomic fallback = 24,788,992 (~99 MB)
  bool big = ws_size >= (size_t)34226176 * 4;

  float* ws = (float*)d_ws;
  long o = 0;
  __hip_bfloat16* xnb   = (__hip_bfloat16*)(ws + o); o += 786432;   // 8192x192 bf16
  __hip_bfloat16* xbufB = (__hip_bfloat16*)(ws + o); o += 1572864;  // 8192x384 bf16
  __hip_bfloat16* zbufB = (__hip_bfloat16*)(ws + o); o += 1572864;
  __hip_bfloat16* xcb   = (__hip_bfloat16*)(ws + o); o += 1572864;
  __hip_bfloat16* Wt1   = (__hip_bfloat16*)(ws + o); o += 73728;    // 768x192 bf16
  __hip_bfloat16* Wt2   = (__hip_bfloat16*)(ws + o); o += 36864;
  __hip_bfloat16* Wt3   = (__hip_bfloat16*)(ws + o); o += 36864;
  float* dtsS           = ws + o;                    o += 393216;   // (BK,p,12) pixel order
  float* BsS            = ws + o;                    o += 524288;   // (BK,p,16)
  float* CsS            = ws + o;                    o += 524288;
  __half* dpre          = (__half*)(ws + o);         o += 6291456;  // (BK,p,384) fp16 delta
  float* Eb             = ws + o;                    o += 6291456;  // (1024 segs, 6144)
  float* Dend           = ws + o;                    o += 393216;   // (1024, 384)
  float* ybuf           = ws + o;                    o += big ? 12582912 : 3145728;
  __hip_bfloat16* yactb = (__hip_bfloat16*)(ws + o); o += 1572864;

  k_ln<<<dim3(2048), dim3(256), 0, stream>>>(input, norm_g, norm_b, xnb);
  k_packw<<<dim3(1152), dim3(256), 0, stream>>>(in_proj_w, x_proj_w, out_proj_w, Wt1, Wt2, Wt3);
  k_gemm_mfma<2><<<dim3(12, 128), dim3(256), 0, stream>>>(xnb, Wt1, nullptr, nullptr, xbufB, zbufB,
                                                          nullptr, nullptr, nullptr, 8192, 768, 192);
  k_conv<<<dim3(8192), dim3(384), 0, stream>>>(xbufB, conv_w, conv_b, xcb);
  k_gemm_mfma<3><<<dim3(3, 128), dim3(256), 0, stream>>>(xcb, Wt2, nullptr, nullptr, nullptr, nullptr,
                                                         dtsS, BsS, CsS, 8192, 192, 384);
  k_dt<<<dim3(1024), dim3(384), 0, stream>>>(dtsS, dt_w, dt_b, dpre);
  k_scan0<<<dim3(1024), dim3(384), 0, stream>>>(dpre, BsS, xcb, A_logs, Eb, Dend);
  k_combine<<<dim3(3072), dim3(128), 0, stream>>>(Eb, Dend, A_logs);
  if (big) {
    k_scan1<0><<<dim3(1024), dim3(384), 0, stream>>>(dpre, BsS, CsS, xcb, A_logs, Eb, ybuf);
    k_merge<1><<<dim3(8192), dim3(384), 0, stream>>>(ybuf, xcb, zbufB, Ds, out_norm_g, out_norm_b, yactb);
  } else {
    hipMemsetAsync(ybuf, 0, (size_t)3145728 * 4, stream);
    k_scan1<1><<<dim3(1024), dim3(384), 0, stream>>>(dpre, BsS, CsS, xcb, A_logs, Eb, ybuf);
    k_merge<0><<<dim3(8192), dim3(384), 0, stream>>>(ybuf, xcb, zbufB, Ds, out_norm_g, out_norm_b, yactb);
  }
  k_gemm_mfma<1><<<dim3(3, 128), dim3(256), 0, stream>>>(yactb, Wt3, input, out, nullptr, nullptr,
                                                         nullptr, nullptr, nullptr, 8192, 192, 384);
}

// Round 5
// 260.433 us; speedup vs baseline: 1.1157x; 1.0046x over previous
//
#include <hip/hip_runtime.h>
#include <hip/hip_bf16.h>
#include <hip/hip_fp16.h>

// VSSBlock: B=2 H=64 W=64 C=192 DM=384 N=16 R=12 K=4 L=4096
// R13 (on R12 base, 261.6us): (1) k_dt packs (du=delta*u, delta) as __half2 plane ->
//     scans drop the xcb gather; (2) Bs/Cs interleaved into one (BK,p,32) array ->
//     one base for scan1's 8 uniform loads; (3) y planes stored bf16 (halves scan1
//     stores + merge reads). Scan structure unchanged (T=32/SEG=128, broadcast VMEM).

typedef __attribute__((ext_vector_type(8))) short short8;     // 8 bf16 = 4 VGPRs
typedef __attribute__((ext_vector_type(4))) float floatx4;    // fp32 accum frag

// ---------------- LayerNorm (pre-norm, eps 1e-6), C=192 -> bf16 ----------------
__global__ __launch_bounds__(256) void k_ln(const float* __restrict__ in,
                                            const float* __restrict__ g,
                                            const float* __restrict__ be,
                                            __hip_bfloat16* __restrict__ out) {
  int row = blockIdx.x * 4 + (threadIdx.x >> 6);
  int lane = threadIdx.x & 63;
  const float* x = in + (long)row * 192;
  float v0 = x[lane], v1 = x[lane + 64], v2 = x[lane + 128];
  float s = v0 + v1 + v2;
  float s2 = v0 * v0 + v1 * v1 + v2 * v2;
  #pragma unroll
  for (int o = 32; o > 0; o >>= 1) { s += __shfl_xor(s, o); s2 += __shfl_xor(s2, o); }
  float mu = s * (1.f / 192.f);
  float var = s2 * (1.f / 192.f) - mu * mu;
  float r = rsqrtf(var + 1e-6f);
  __hip_bfloat16* op = out + (long)row * 192;
  op[lane]       = __float2bfloat16((v0 - mu) * r * g[lane]       + be[lane]);
  op[lane + 64]  = __float2bfloat16((v1 - mu) * r * g[lane + 64]  + be[lane + 64]);
  op[lane + 128] = __float2bfloat16((v2 - mu) * r * g[lane + 128] + be[lane + 128]);
}

// ---------------- pack weights -> bf16, transposed to (N x K) ----------------
__global__ __launch_bounds__(256) void k_packw(const float* __restrict__ ipw,
                                               const float* __restrict__ xpw,
                                               const float* __restrict__ opw,
                                               __hip_bfloat16* __restrict__ Wt1,
                                               __hip_bfloat16* __restrict__ Wt2,
                                               __hip_bfloat16* __restrict__ Wt3) {
  int idx = blockIdx.x * 256 + threadIdx.x;
  if (idx < 147456) {                       // Wt1[n][k] = ipw[k][n]
    int n = idx / 192, k = idx - n * 192;
    Wt1[idx] = __float2bfloat16(ipw[(long)k * 768 + n]);
  } else if (idx < 147456 + 73728) {        // Wt2[j][d]
    int t = idx - 147456;
    int j = t / 384;
    float v = (j < 176) ? xpw[t] : 0.f;
    Wt2[t] = __float2bfloat16(v);
  } else if (idx < 147456 + 73728 + 73728) {// Wt3[n][k] = opw[k][n]
    int t = idx - 147456 - 73728;
    int n = t / 384, k = t - n * 384;
    Wt3[t] = __float2bfloat16(opw[(long)k * 192 + n]);
  }
}

// direction map (involutions): pixel p <-> scan position l
__device__ __forceinline__ int inv_dir(int k, int p) {
  int pt = ((p & 63) << 6) | (p >> 6);
  if (k == 0) return p;
  if (k == 1) return pt;
  if (k == 2) return 4095 - p;
  return 4095 - pt;
}
__device__ __forceinline__ int dir_pix(int k, int l) { return inv_dir(k, l); }

// ---------------- bf16 MFMA GEMM: 64x64 tile, BK=64, XOR-swizzled LDS ----------------
template <int EPI>
__global__ __launch_bounds__(256) void k_gemm_mfma(const __hip_bfloat16* __restrict__ A,
                                                   const __hip_bfloat16* __restrict__ Bt,
                                                   const float* __restrict__ Res,
                                                   float* __restrict__ Co,
                                                   __hip_bfloat16* __restrict__ CoB,
                                                   __hip_bfloat16* __restrict__ Co2B,
                                                   float* __restrict__ dtsS,
                                                   float* __restrict__ BCs,
                                                   int M, int N, int Kk) {
  __shared__ __align__(16) short As[64 * 64];
  __shared__ __align__(16) short Bs[64 * 64];
  int tid = threadIdx.x;
  int wave = tid >> 6, lane = tid & 63;
  int mlane = lane & 15, quad = lane >> 4;
  int row0 = blockIdx.y * 64, col0 = blockIdx.x * 64;
  int wr = wave & 1, wc = wave >> 1;
  floatx4 acc[2][2];
  #pragma unroll
  for (int mi = 0; mi < 2; mi++)
    #pragma unroll
    for (int ni = 0; ni < 2; ni++) acc[mi][ni] = (floatx4){0.f, 0.f, 0.f, 0.f};

  for (int k0 = 0; k0 < Kk; k0 += 64) {
    #pragma unroll
    for (int c = tid; c < 512; c += 256) {
      int r = c >> 3, j = c & 7;
      *(float4*)&As[r * 64 + ((j ^ (r & 7)) << 3)] =
          *(const float4*)&A[(long)(row0 + r) * Kk + k0 + j * 8];
    }
    #pragma unroll
    for (int c = tid; c < 512; c += 256) {
      int r = c >> 3, j = c & 7;
      *(float4*)&Bs[r * 64 + ((j ^ (r & 7)) << 3)] =
          *(const float4*)&Bt[(long)(col0 + r) * Kk + k0 + j * 8];
    }
    __syncthreads();
    short8 af[2][2], bf[2][2];
    #pragma unroll
    for (int mi = 0; mi < 2; mi++) {
      int r = wr * 32 + mi * 16 + mlane;
      #pragma unroll
      for (int kk = 0; kk < 2; kk++) {
        int jx = (kk * 4 + quad) ^ (r & 7);
        af[mi][kk] = *(const short8*)&As[r * 64 + jx * 8];
      }
    }
    #pragma unroll
    for (int ni = 0; ni < 2; ni++) {
      int rn = wc * 32 + ni * 16 + mlane;
      #pragma unroll
      for (int kk = 0; kk < 2; kk++) {
        int jx = (kk * 4 + quad) ^ (rn & 7);
        bf[ni][kk] = *(const short8*)&Bs[rn * 64 + jx * 8];
      }
    }
    #pragma unroll
    for (int kk = 0; kk < 2; kk++)
      #pragma unroll
      for (int mi = 0; mi < 2; mi++)
        #pragma unroll
        for (int ni = 0; ni < 2; ni++)
          acc[mi][ni] = __builtin_amdgcn_mfma_f32_16x16x32_bf16(af[mi][kk], bf[ni][kk],
                                                                acc[mi][ni], 0, 0, 0);
    __syncthreads();
  }
  // C/D layout: col=lane&15, row=quad*4+reg  [m89-verified]
  #pragma unroll
  for (int mi = 0; mi < 2; mi++) {
    #pragma unroll
    for (int ni = 0; ni < 2; ni++) {
      int cc = col0 + wc * 32 + ni * 16 + mlane;
      #pragma unroll
      for (int i = 0; i < 4; i++) {
        int rr = row0 + wr * 32 + mi * 16 + quad * 4 + i;
        float v = acc[mi][ni][i];
        if (EPI == 1) {
          Co[(long)rr * N + cc] = v + Res[(long)rr * N + cc];
        } else if (EPI == 2) {
          if (cc < 384) CoB[(long)rr * 384 + cc] = __float2bfloat16(v);
          else          Co2B[(long)rr * 384 + (cc - 384)] = __float2bfloat16(v);
        } else {  // EPI == 3: pixel-order split; B at 0..15, C at 16..31 of BCs row
          if (cc < 176) {
            int k4 = (cc >= 132) ? 3 : (cc >= 88) ? 2 : (cc >= 44) ? 1 : 0;
            int c = cc - k4 * 44;
            int b = rr >> 12, p = rr & 4095;
            long lbase = ((long)((b << 2) + k4) << 12) + p;   // pixel order
            if (c < 12) dtsS[lbase * 12 + c] = v;
            else        BCs[lbase * 32 + (c - 12)] = v;
          }
        }
      }
    }
  }
}

// ---------------- depthwise 3x3 conv + bias + SiLU; bf16 in, bf16 out ----------------
__global__ __launch_bounds__(384) void k_conv(const __hip_bfloat16* __restrict__ xbufB,
                                              const float* __restrict__ cw,
                                              const float* __restrict__ cb,
                                              __hip_bfloat16* __restrict__ xcb) {
  int row = blockIdx.x;
  int b = row >> 12, p = row & 4095;
  int h = p >> 6, w0 = p & 63;
  int d = threadIdx.x;
  float acc = cb[d];
  const float* wt = cw + d * 9;
  #pragma unroll
  for (int dh = -1; dh <= 1; dh++) {
    int hh = h + dh;
    if (hh < 0 || hh > 63) continue;
    #pragma unroll
    for (int dw = -1; dw <= 1; dw++) {
      int ww = w0 + dw;
      if (ww < 0 || ww > 63) continue;
      acc += __bfloat162float(xbufB[((long)(b << 12) + (hh << 6) + ww) * 384 + d])
             * wt[(dh + 1) * 3 + (dw + 1)];
    }
  }
  float sg = 1.f / (1.f + __expf(-acc));
  xcb[(long)row * 384 + d] = __float2bfloat16(acc * sg);
}

// ---------------- dt precompute: (du = delta*u, delta) -> __half2 plane ----------------
// grid: (bk, 128 chunks of 32 pixels); 384 threads (one per d). Pixel-order, coalesced.
__global__ __launch_bounds__(384) void k_dt(const float* __restrict__ dtsS,
                                            const float* __restrict__ dt_w,
                                            const float* __restrict__ dt_b,
                                            const __hip_bfloat16* __restrict__ xcb,
                                            __half2* __restrict__ dpre) {
  int bid = blockIdx.x;
  int chunk = bid & 127, bk = bid >> 7;
  int k = bk & 3, b = bk >> 2;
  int d = threadIdx.x;
  float w[12];
  const float* dwp = dt_w + ((long)(k * 384) + d) * 12;
  #pragma unroll
  for (int r = 0; r < 12; r++) w[r] = dwp[r];
  float db = dt_b[k * 384 + d];
  long base = ((long)bk << 12) + chunk * 32;
  long pbase = ((long)(b << 12)) + chunk * 32;
  #pragma unroll 4
  for (int t = 0; t < 32; t++) {
    const float4* dq = (const float4*)(dtsS + (base + t) * 12);
    float4 q0 = dq[0], q1 = dq[1], q2 = dq[2];
    float x = db + q0.x * w[0] + q0.y * w[1] + q0.z * w[2] + q0.w * w[3]
                 + q1.x * w[4] + q1.y * w[5] + q1.z * w[6] + q1.w * w[7]
                 + q2.x * w[8] + q2.y * w[9] + q2.z * w[10] + q2.w * w[11];
    float e = __expf(x);
    float delta = (x > 15.f) ? x : __logf(1.f + e);
    float u = __bfloat162float(xcb[(pbase + t) * 384 + d]);
    __half2 o;
    o.x = __float2half(delta * u);
    o.y = __float2half(delta);
    dpre[(base + t) * 384 + d] = o;
  }
}

// powers: pws[n] = r^(n+1), log-depth pairing
__device__ __forceinline__ void pow16(float r, float* pws) {
  pws[0] = r;
  #pragma unroll
  for (int n = 1; n < 16; n++) {
    int m = n + 1, c = (m + 1) / 2, f = m - c;
    pws[n] = pws[c - 1] * pws[f - 1];
  }
}

// ---------------- scan pass 0: 128 segments x 32 steps; E[16] + scalar cumDelta ----------------
__global__ __launch_bounds__(384) void k_scan0(
    const __half2* __restrict__ dpre, const float* __restrict__ BCs,
    const float* __restrict__ A_logs,
    float* __restrict__ Eb, float* __restrict__ Dend) {
  int bid = blockIdx.x;
  int s = bid & 127, bk = bid >> 7;
  int k = bk & 3;
  int d = threadIdx.x;
  const float* al = A_logs + ((long)(k * 384) + d) * 16;
  bool pw = true;
  float av[16];
  #pragma unroll
  for (int n = 0; n < 16; n++) {
    float a = __expf(al[n]);
    av[n] = -a;
    pw = pw && (fabsf(a - (float)(n + 1)) < 1e-3f);
  }
  float h[16];
  #pragma unroll
  for (int n = 0; n < 16; n++) h[n] = 0.f;
  float cum = 0.f;
  long bpk = (long)bk << 12;

  if (pw) {
    #pragma unroll 4
    for (int t = 0; t < 32; t++) {
      int p = dir_pix(k, s * 32 + t);
      __half2 v = dpre[(bpk + p) * 384 + d];
      float du = __half2float(v.x);
      float delta = __half2float(v.y);
      cum += delta;
      float rr = __expf(-delta);
      float pws[16]; pow16(rr, pws);
      const float4* Bq = (const float4*)(BCs + (bpk + p) * 32);
      float4 b0 = Bq[0], b1 = Bq[1], b2 = Bq[2], b3 = Bq[3];
      float Bl[16] = {b0.x, b0.y, b0.z, b0.w, b1.x, b1.y, b1.z, b1.w,
                      b2.x, b2.y, b2.z, b2.w, b3.x, b3.y, b3.z, b3.w};
      #pragma unroll
      for (int n = 0; n < 16; n++) h[n] = pws[n] * h[n] + du * Bl[n];
    }
  } else {
    for (int t = 0; t < 32; t++) {
      int p = dir_pix(k, s * 32 + t);
      __half2 v = dpre[(bpk + p) * 384 + d];
      float du = __half2float(v.x);
      float delta = __half2float(v.y);
      cum += delta;
      const float4* Bq = (const float4*)(BCs + (bpk + p) * 32);
      float4 b0 = Bq[0], b1 = Bq[1], b2 = Bq[2], b3 = Bq[3];
      float Bl[16] = {b0.x, b0.y, b0.z, b0.w, b1.x, b1.y, b1.z, b1.w,
                      b2.x, b2.y, b2.z, b2.w, b3.x, b3.y, b3.z, b3.w};
      #pragma unroll
      for (int n = 0; n < 16; n++) {
        float dA = __expf(delta * av[n]);
        h[n] = dA * h[n] + du * Bl[n];
      }
    }
  }
  long g = (long)bk * 128 + s;
  float* Ep = Eb + g * 6144 + d * 16;
  #pragma unroll
  for (int n = 0; n < 16; n++) Ep[n] = h[n];
  Dend[g * 384 + d] = cum;
}

// ---------------- combine: Kogge-Stone over 128 segments; pow16 trick ----------------
__global__ __launch_bounds__(128) void k_combine(float* __restrict__ Eb,
                                                 const float* __restrict__ Dend,
                                                 const float* __restrict__ A_logs) {
  int bid = blockIdx.x;            // bk*384 + d, 3072 blocks
  int bk = bid / 384;
  int d = bid - bk * 384;
  int k = bk & 3;
  int s = threadIdx.x;             // segment 0..127
  const float* al = A_logs + ((long)(k * 384) + d) * 16;
  bool pw = true;
  float av[16];
  #pragma unroll
  for (int n = 0; n < 16; n++) {
    float a = __expf(al[n]);
    av[n] = -a;
    pw = pw && (fabsf(a - (float)(n + 1)) < 1e-3f);
  }

  long ebase = ((long)bk * 128 + s) * 6144 + d * 16;
  float e[16];
  *(float4*)&e[0]  = *(const float4*)&Eb[ebase + 0];
  *(float4*)&e[4]  = *(const float4*)&Eb[ebase + 4];
  *(float4*)&e[8]  = *(const float4*)&Eb[ebase + 8];
  *(float4*)&e[12] = *(const float4*)&Eb[ebase + 12];
  float sig = Dend[((long)bk * 128 + s) * 384 + d];

  __shared__ float sE[128][17];    // [s][0]=sigma, [s][1..16]=e
  sE[s][0] = sig;
  #pragma unroll
  for (int n = 0; n < 16; n++) sE[s][1 + n] = e[n];
  __syncthreads();

  for (int o = 1; o < 128; o <<= 1) {
    float ps = 0.f, pe[16];
    bool act = (s >= o);
    if (act) {
      ps = sE[s - o][0];
      #pragma unroll
      for (int n = 0; n < 16; n++) pe[n] = sE[s - o][1 + n];
    }
    __syncthreads();
    if (act) {
      if (pw) {
        float rc = __expf(-sig);
        float pwr[16]; pow16(rc, pwr);      // pwr[n] = exp(av[n]*sig), av[n]=-(n+1)
        #pragma unroll
        for (int n = 0; n < 16; n++) e[n] += pwr[n] * pe[n];
      } else {
        #pragma unroll
        for (int n = 0; n < 16; n++) e[n] += __expf(av[n] * sig) * pe[n];
      }
      sig += ps;
      sE[s][0] = sig;
      #pragma unroll
      for (int n = 0; n < 16; n++) sE[s][1 + n] = e[n];
    }
    __syncthreads();
  }

  float ho[16];
  if (s == 0) {
    #pragma unroll
    for (int n = 0; n < 16; n++) ho[n] = 0.f;
  } else {
    #pragma unroll
    for (int n = 0; n < 16; n++) ho[n] = sE[s - 1][1 + n];
  }
  *(float4*)&Eb[ebase + 0]  = *(float4*)&ho[0];
  *(float4*)&Eb[ebase + 4]  = *(float4*)&ho[4];
  *(float4*)&Eb[ebase + 8]  = *(float4*)&ho[8];
  *(float4*)&Eb[ebase + 12] = *(float4*)&ho[12];
}

// ---------------- scan pass 1: full recurrence from h_in (in Eb) ----------------
// ATOMIC=0: store y bf16 into per-direction plane ybufB. ATOMIC=1: fp32 atomicAdd ysum.
template <int ATOMIC>
__global__ __launch_bounds__(384) void k_scan1(
    const __half2* __restrict__ dpre, const float* __restrict__ BCs,
    const float* __restrict__ A_logs, const float* __restrict__ Eb,
    __hip_bfloat16* __restrict__ ybufB, float* __restrict__ ysum) {
  int bid = blockIdx.x;
  int s = bid & 127, bk = bid >> 7;
  int k = bk & 3, b = bk >> 2;
  int d = threadIdx.x;
  const float* al = A_logs + ((long)(k * 384) + d) * 16;
  bool pw = true;
  float av[16];
  #pragma unroll
  for (int n = 0; n < 16; n++) {
    float a = __expf(al[n]);
    av[n] = -a;
    pw = pw && (fabsf(a - (float)(n + 1)) < 1e-3f);
  }
  float h[16];
  const float* hp = Eb + ((long)bk * 128 + s) * 6144 + d * 16;
  #pragma unroll
  for (int n = 0; n < 16; n++) h[n] = hp[n];
  long bpk = (long)bk << 12;
  long bpix = (long)(b << 12);

  if (pw) {
    #pragma unroll 4
    for (int t = 0; t < 32; t++) {
      int p = dir_pix(k, s * 32 + t);
      __half2 v = dpre[(bpk + p) * 384 + d];
      float du = __half2float(v.x);
      float delta = __half2float(v.y);
      float rr = __expf(-delta);
      float pws[16]; pow16(rr, pws);
      const float4* Bq = (const float4*)(BCs + (bpk + p) * 32);
      float4 b0 = Bq[0], b1 = Bq[1], b2 = Bq[2], b3 = Bq[3];
      float Bl[16] = {b0.x, b0.y, b0.z, b0.w, b1.x, b1.y, b1.z, b1.w,
                      b2.x, b2.y, b2.z, b2.w, b3.x, b3.y, b3.z, b3.w};
      const float4* Cq = Bq + 4;
      float4 c0 = Cq[0], c1 = Cq[1], c2 = Cq[2], c3 = Cq[3];
      float Cl[16] = {c0.x, c0.y, c0.z, c0.w, c1.x, c1.y, c1.z, c1.w,
                      c2.x, c2.y, c2.z, c2.w, c3.x, c3.y, c3.z, c3.w};
      float y = 0.f;
      #pragma unroll
      for (int n = 0; n < 16; n++) { h[n] = pws[n] * h[n] + du * Bl[n]; y += h[n] * Cl[n]; }
      if (ATOMIC) atomicAdd(&ysum[(bpix + p) * 384 + d], y);
      else        ybufB[(bpk + p) * 384 + d] = __float2bfloat16(y);
    }
  } else {
    for (int t = 0; t < 32; t++) {
      int p = dir_pix(k, s * 32 + t);
      __half2 v = dpre[(bpk + p) * 384 + d];
      float du = __half2float(v.x);
      float delta = __half2float(v.y);
      const float4* Bq = (const float4*)(BCs + (bpk + p) * 32);
      float4 b0 = Bq[0], b1 = Bq[1], b2 = Bq[2], b3 = Bq[3];
      float Bl[16] = {b0.x, b0.y, b0.z, b0.w, b1.x, b1.y, b1.z, b1.w,
                      b2.x, b2.y, b2.z, b2.w, b3.x, b3.y, b3.z, b3.w};
      const float4* Cq = Bq + 4;
      float4 c0 = Cq[0], c1 = Cq[1], c2 = Cq[2], c3 = Cq[3];
      float Cl[16] = {c0.x, c0.y, c0.z, c0.w, c1.x, c1.y, c1.z, c1.w,
                      c2.x, c2.y, c2.z, c2.w, c3.x, c3.y, c3.z, c3.w};
      float y = 0.f;
      #pragma unroll
      for (int n = 0; n < 16; n++) {
        float dA = __expf(delta * av[n]);
        h[n] = dA * h[n] + du * Bl[n];
        y += h[n] * Cl[n];
      }
      if (ATOMIC) atomicAdd(&ysum[(bpix + p) * 384 + d], y);
      else        ybufB[(bpk + p) * 384 + d] = __float2bfloat16(y);
    }
  }
}

// ---------------- merge: y + D-skip(bf16 xcb) + out-LN + silu(z bf16) -> bf16 ----------------
template <int GATHER>
__global__ __launch_bounds__(384) void k_merge(const __hip_bfloat16* __restrict__ yinB,
                                               const float* __restrict__ yinF,
                                               const __hip_bfloat16* __restrict__ xcb,
                                               const __hip_bfloat16* __restrict__ zbufB,
                                               const float* __restrict__ Ds,
                                               const float* __restrict__ g,
                                               const float* __restrict__ be,
                                               __hip_bfloat16* __restrict__ yactb) {
  int row = blockIdx.x;
  int d = threadIdx.x;
  float v;
  if (GATHER) {
    int b = row >> 12, p = row & 4095;
    long base = ((long)(b << 2) << 12) + p;  // plane (b*4+k)*4096 + p
    v = __bfloat162float(yinB[base * 384 + d])
      + __bfloat162float(yinB[(base + 4096) * 384 + d])
      + __bfloat162float(yinB[(base + 8192) * 384 + d])
      + __bfloat162float(yinB[(base + 12288) * 384 + d]);
  } else {
    v = yinF[(long)row * 384 + d];
  }
  float sd = Ds[d] + Ds[384 + d] + Ds[768 + d] + Ds[1152 + d];
  v += __bfloat162float(xcb[(long)row * 384 + d]) * sd;
  float s1 = v, s2 = v * v;
  #pragma unroll
  for (int o = 32; o > 0; o >>= 1) { s1 += __shfl_xor(s1, o); s2 += __shfl_xor(s2, o); }
  __shared__ float r1[6], r2[6];
  int wv = threadIdx.x >> 6;
  if ((threadIdx.x & 63) == 0) { r1[wv] = s1; r2[wv] = s2; }
  __syncthreads();
  float S1 = 0.f, S2 = 0.f;
  #pragma unroll
  for (int i = 0; i < 6; i++) { S1 += r1[i]; S2 += r2[i]; }
  float mu = S1 * (1.f / 384.f);
  float var = S2 * (1.f / 384.f) - mu * mu;
  float rr = rsqrtf(var + 1e-5f);
  float yn = (v - mu) * rr * g[d] + be[d];
  float z = __bfloat162float(zbufB[(long)row * 384 + d]);
  float sg = z / (1.f + __expf(-z));
  yactb[(long)row * 384 + d] = __float2bfloat16(yn * sg);
}

extern "C" void kernel_launch(void* const* d_in, const int* in_sizes, int n_in,
                              void* d_out, int out_size, void* d_ws, size_t ws_size,
                              hipStream_t stream) {
  const float* input      = (const float*)d_in[0];
  const float* norm_g     = (const float*)d_in[1];
  const float* norm_b     = (const float*)d_in[2];
  const float* in_proj_w  = (const float*)d_in[3];
  const float* conv_w     = (const float*)d_in[4];
  const float* conv_b     = (const float*)d_in[5];
  const float* x_proj_w   = (const float*)d_in[6];
  const float* dt_w       = (const float*)d_in[7];
  const float* dt_b       = (const float*)d_in[8];
  const float* A_logs     = (const float*)d_in[9];
  const float* Ds         = (const float*)d_in[10];
  const float* out_norm_g = (const float*)d_in[11];
  const float* out_norm_b = (const float*)d_in[12];
  const float* out_proj_w = (const float*)d_in[13];
  float* out = (float*)d_out;

  // plane path total = 34,226,176 floats (~137 MB); atomic fallback = 31,080,448 (~124 MB)
  bool big = ws_size >= (size_t)34226176 * 4;

  float* ws = (float*)d_ws;
  long o = 0;
  __hip_bfloat16* xnb   = (__hip_bfloat16*)(ws + o); o += 786432;   // 8192x192 bf16
  __hip_bfloat16* xbufB = (__hip_bfloat16*)(ws + o); o += 1572864;  // 8192x384 bf16
  __hip_bfloat16* zbufB = (__hip_bfloat16*)(ws + o); o += 1572864;
  __hip_bfloat16* xcb   = (__hip_bfloat16*)(ws + o); o += 1572864;
  __hip_bfloat16* Wt1   = (__hip_bfloat16*)(ws + o); o += 73728;    // 768x192 bf16
  __hip_bfloat16* Wt2   = (__hip_bfloat16*)(ws + o); o += 36864;
  __hip_bfloat16* Wt3   = (__hip_bfloat16*)(ws + o); o += 36864;
  float* dtsS           = ws + o;                    o += 393216;   // (BK,p,12) pixel order
  float* BCs            = ws + o;                    o += 1048576;  // (BK,p,32): B|C interleaved
  __half2* dpre         = (__half2*)(ws + o);        o += 12582912; // (BK,p,384) (du,delta)
  float* Eb             = ws + o;                    o += 6291456;  // (1024 segs, 6144)
  float* Dend           = ws + o;                    o += 393216;   // (1024, 384)
  __hip_bfloat16* ybufB = (__hip_bfloat16*)(ws + o);
  float* ysum           = ws + o;                    o += big ? 6291456 : 3145728;
  __hip_bfloat16* yactb = (__hip_bfloat16*)(ws + o); o += 1572864;

  k_ln<<<dim3(2048), dim3(256), 0, stream>>>(input, norm_g, norm_b, xnb);
  k_packw<<<dim3(1152), dim3(256), 0, stream>>>(in_proj_w, x_proj_w, out_proj_w, Wt1, Wt2, Wt3);
  k_gemm_mfma<2><<<dim3(12, 128), dim3(256), 0, stream>>>(xnb, Wt1, nullptr, nullptr, xbufB, zbufB,
                                                          nullptr, nullptr, 8192, 768, 192);
  k_conv<<<dim3(8192), dim3(384), 0, stream>>>(xbufB, conv_w, conv_b, xcb);
  k_gemm_mfma<3><<<dim3(3, 128), dim3(256), 0, stream>>>(xcb, Wt2, nullptr, nullptr, nullptr, nullptr,
                                                         dtsS, BCs, 8192, 192, 384);
  k_dt<<<dim3(1024), dim3(384), 0, stream>>>(dtsS, dt_w, dt_b, xcb, dpre);
  k_scan0<<<dim3(1024), dim3(384), 0, stream>>>(dpre, BCs, A_logs, Eb, Dend);
  k_combine<<<dim3(3072), dim3(128), 0, stream>>>(Eb, Dend, A_logs);
  if (big) {
    k_scan1<0><<<dim3(1024), dim3(384), 0, stream>>>(dpre, BCs, A_logs, Eb, ybufB, nullptr);
    k_merge<1><<<dim3(8192), dim3(384), 0, stream>>>(ybufB, nullptr, xcb, zbufB, Ds,
                                                     out_norm_g, out_norm_b, yactb);
  } else {
    hipMemsetAsync(ysum, 0, (size_t)3145728 * 4, stream);
    k_scan1<1><<<dim3(1024), dim3(384), 0, stream>>>(dpre, BCs, A_logs, Eb, nullptr, ysum);
    k_merge<0><<<dim3(8192), dim3(384), 0, stream>>>(nullptr, ysum, xcb, zbufB, Ds,
                                                     out_norm_g, out_norm_b, yactb);
  }
  k_gemm_mfma<1><<<dim3(3, 128), dim3(256), 0, stream>>>(yactb, Wt3, input, out, nullptr, nullptr,
                                                         nullptr, nullptr, 8192, 192, 384);
}

// Round 6
// 244.150 us; speedup vs baseline: 1.1901x; 1.0667x over previous
//
#include <hip/hip_runtime.h>
#include <hip/hip_bf16.h>
#include <hip/hip_fp16.h>

// VSSBlock: B=2 H=64 W=64 C=192 DM=384 N=16 R=12 K=4 L=4096
// R14 (on R13 base, 260.4us): (1) conv tiled 4 pixels/block (18 loads per 4 outputs vs 36);
//     (2) dpre back to delta-only __half (25MB; u-gather in scans proven ~free in R13);
//     (3) gemm<2> uses 64x128 tile (halves A re-reads across the N=768 width).
//     Scan structure (T=32/SEG=128, broadcast VMEM, BCs interleaved, bf16 y) unchanged.

typedef __attribute__((ext_vector_type(8))) short short8;     // 8 bf16 = 4 VGPRs
typedef __attribute__((ext_vector_type(4))) float floatx4;    // fp32 accum frag

// ---------------- LayerNorm (pre-norm, eps 1e-6), C=192 -> bf16 ----------------
__global__ __launch_bounds__(256) void k_ln(const float* __restrict__ in,
                                            const float* __restrict__ g,
                                            const float* __restrict__ be,
                                            __hip_bfloat16* __restrict__ out) {
  int row = blockIdx.x * 4 + (threadIdx.x >> 6);
  int lane = threadIdx.x & 63;
  const float* x = in + (long)row * 192;
  float v0 = x[lane], v1 = x[lane + 64], v2 = x[lane + 128];
  float s = v0 + v1 + v2;
  float s2 = v0 * v0 + v1 * v1 + v2 * v2;
  #pragma unroll
  for (int o = 32; o > 0; o >>= 1) { s += __shfl_xor(s, o); s2 += __shfl_xor(s2, o); }
  float mu = s * (1.f / 192.f);
  float var = s2 * (1.f / 192.f) - mu * mu;
  float r = rsqrtf(var + 1e-6f);
  __hip_bfloat16* op = out + (long)row * 192;
  op[lane]       = __float2bfloat16((v0 - mu) * r * g[lane]       + be[lane]);
  op[lane + 64]  = __float2bfloat16((v1 - mu) * r * g[lane + 64]  + be[lane + 64]);
  op[lane + 128] = __float2bfloat16((v2 - mu) * r * g[lane + 128] + be[lane + 128]);
}

// ---------------- pack weights -> bf16, transposed to (N x K) ----------------
__global__ __launch_bounds__(256) void k_packw(const float* __restrict__ ipw,
                                               const float* __restrict__ xpw,
                                               const float* __restrict__ opw,
                                               __hip_bfloat16* __restrict__ Wt1,
                                               __hip_bfloat16* __restrict__ Wt2,
                                               __hip_bfloat16* __restrict__ Wt3) {
  int idx = blockIdx.x * 256 + threadIdx.x;
  if (idx < 147456) {                       // Wt1[n][k] = ipw[k][n]
    int n = idx / 192, k = idx - n * 192;
    Wt1[idx] = __float2bfloat16(ipw[(long)k * 768 + n]);
  } else if (idx < 147456 + 73728) {        // Wt2[j][d]
    int t = idx - 147456;
    int j = t / 384;
    float v = (j < 176) ? xpw[t] : 0.f;
    Wt2[t] = __float2bfloat16(v);
  } else if (idx < 147456 + 73728 + 73728) {// Wt3[n][k] = opw[k][n]
    int t = idx - 147456 - 73728;
    int n = t / 384, k = t - n * 384;
    Wt3[t] = __float2bfloat16(opw[(long)k * 192 + n]);
  }
}

// direction map (involutions): pixel p <-> scan position l
__device__ __forceinline__ int inv_dir(int k, int p) {
  int pt = ((p & 63) << 6) | (p >> 6);
  if (k == 0) return p;
  if (k == 1) return pt;
  if (k == 2) return 4095 - p;
  return 4095 - pt;
}
__device__ __forceinline__ int dir_pix(int k, int l) { return inv_dir(k, l); }

// ---------------- bf16 MFMA GEMM: 64xTN tile, BK=64, XOR-swizzled LDS ----------------
// 4 waves 2x2; wave tile 32 x (TN/2) = 2 x (TN/32) frags of 16x16x32.
template <int EPI, int TN>
__global__ __launch_bounds__(256) void k_gemm_mfma(const __hip_bfloat16* __restrict__ A,
                                                   const __hip_bfloat16* __restrict__ Bt,
                                                   const float* __restrict__ Res,
                                                   float* __restrict__ Co,
                                                   __hip_bfloat16* __restrict__ CoB,
                                                   __hip_bfloat16* __restrict__ Co2B,
                                                   float* __restrict__ dtsS,
                                                   float* __restrict__ BCs,
                                                   int M, int N, int Kk) {
  constexpr int NI = TN / 32;                 // frags per wave in N
  __shared__ __align__(16) short As[64 * 64];
  __shared__ __align__(16) short Bs[TN * 64];
  int tid = threadIdx.x;
  int wave = tid >> 6, lane = tid & 63;
  int mlane = lane & 15, quad = lane >> 4;
  int row0 = blockIdx.y * 64, col0 = blockIdx.x * TN;
  int wr = wave & 1, wc = wave >> 1;
  floatx4 acc[2][NI];
  #pragma unroll
  for (int mi = 0; mi < 2; mi++)
    #pragma unroll
    for (int ni = 0; ni < NI; ni++) acc[mi][ni] = (floatx4){0.f, 0.f, 0.f, 0.f};

  for (int k0 = 0; k0 < Kk; k0 += 64) {
    #pragma unroll
    for (int c = tid; c < 512; c += 256) {
      int r = c >> 3, j = c & 7;
      *(float4*)&As[r * 64 + ((j ^ (r & 7)) << 3)] =
          *(const float4*)&A[(long)(row0 + r) * Kk + k0 + j * 8];
    }
    #pragma unroll
    for (int c = tid; c < TN * 8; c += 256) {
      int r = c >> 3, j = c & 7;
      *(float4*)&Bs[r * 64 + ((j ^ (r & 7)) << 3)] =
          *(const float4*)&Bt[(long)(col0 + r) * Kk + k0 + j * 8];
    }
    __syncthreads();
    short8 af[2][2], bf[NI][2];
    #pragma unroll
    for (int mi = 0; mi < 2; mi++) {
      int r = wr * 32 + mi * 16 + mlane;
      #pragma unroll
      for (int kk = 0; kk < 2; kk++) {
        int jx = (kk * 4 + quad) ^ (r & 7);
        af[mi][kk] = *(const short8*)&As[r * 64 + jx * 8];
      }
    }
    #pragma unroll
    for (int ni = 0; ni < NI; ni++) {
      int rn = wc * (TN / 2) + ni * 16 + mlane;
      #pragma unroll
      for (int kk = 0; kk < 2; kk++) {
        int jx = (kk * 4 + quad) ^ (rn & 7);
        bf[ni][kk] = *(const short8*)&Bs[rn * 64 + jx * 8];
      }
    }
    #pragma unroll
    for (int kk = 0; kk < 2; kk++)
      #pragma unroll
      for (int mi = 0; mi < 2; mi++)
        #pragma unroll
        for (int ni = 0; ni < NI; ni++)
          acc[mi][ni] = __builtin_amdgcn_mfma_f32_16x16x32_bf16(af[mi][kk], bf[ni][kk],
                                                                acc[mi][ni], 0, 0, 0);
    __syncthreads();
  }
  // C/D layout: col=lane&15, row=quad*4+reg  [m89-verified]
  #pragma unroll
  for (int mi = 0; mi < 2; mi++) {
    #pragma unroll
    for (int ni = 0; ni < NI; ni++) {
      int cc = col0 + wc * (TN / 2) + ni * 16 + mlane;
      #pragma unroll
      for (int i = 0; i < 4; i++) {
        int rr = row0 + wr * 32 + mi * 16 + quad * 4 + i;
        float v = acc[mi][ni][i];
        if (EPI == 1) {
          Co[(long)rr * N + cc] = v + Res[(long)rr * N + cc];
        } else if (EPI == 2) {
          if (cc < 384) CoB[(long)rr * 384 + cc] = __float2bfloat16(v);
          else          Co2B[(long)rr * 384 + (cc - 384)] = __float2bfloat16(v);
        } else {  // EPI == 3: pixel-order split; B at 0..15, C at 16..31 of BCs row
          if (cc < 176) {
            int k4 = (cc >= 132) ? 3 : (cc >= 88) ? 2 : (cc >= 44) ? 1 : 0;
            int c = cc - k4 * 44;
            int b = rr >> 12, p = rr & 4095;
            long lbase = ((long)((b << 2) + k4) << 12) + p;   // pixel order
            if (c < 12) dtsS[lbase * 12 + c] = v;
            else        BCs[lbase * 32 + (c - 12)] = v;
          }
        }
      }
    }
  }
}

// ---------------- depthwise 3x3 conv + bias + SiLU; 4 pixels/block; bf16 in/out ----------------
__global__ __launch_bounds__(384) void k_conv(const __hip_bfloat16* __restrict__ xbufB,
                                              const float* __restrict__ cw,
                                              const float* __restrict__ cb,
                                              __hip_bfloat16* __restrict__ xcb) {
  int blk = blockIdx.x;            // 2048: b(2) x h(64) x wgroup(16)
  int wg = blk & 15, h = (blk >> 4) & 63, b = blk >> 10;
  int w0 = wg * 4;
  int d = threadIdx.x;
  float wt[9];
  const float* wp = cw + d * 9;
  #pragma unroll
  for (int i = 0; i < 9; i++) wt[i] = wp[i];
  float bias = cb[d];
  float v[3][6];
  #pragma unroll
  for (int r = 0; r < 3; r++) {
    int hh = h + r - 1;
    bool rok = (hh >= 0) && (hh < 64);
    #pragma unroll
    for (int c = 0; c < 6; c++) {
      int ww = w0 + c - 1;
      bool ok = rok && (ww >= 0) && (ww < 64);
      v[r][c] = ok ? __bfloat162float(xbufB[((long)(b << 12) + (hh << 6) + ww) * 384 + d]) : 0.f;
    }
  }
  #pragma unroll
  for (int i = 0; i < 4; i++) {
    float acc = bias;
    #pragma unroll
    for (int r = 0; r < 3; r++)
      #pragma unroll
      for (int c = 0; c < 3; c++)
        acc += v[r][i + c] * wt[r * 3 + c];
    float sg = 1.f / (1.f + __expf(-acc));
    xcb[((long)(b << 12) + (h << 6) + (w0 + i)) * 384 + d] = __float2bfloat16(acc * sg);
  }
}

// ---------------- dt precompute: delta = softplus(dts @ dt_w^T + dt_b) -> fp16 plane ----------------
__global__ __launch_bounds__(384) void k_dt(const float* __restrict__ dtsS,
                                            const float* __restrict__ dt_w,
                                            const float* __restrict__ dt_b,
                                            __half* __restrict__ dpre) {
  int bid = blockIdx.x;
  int chunk = bid & 127, bk = bid >> 7;
  int k = bk & 3;
  int d = threadIdx.x;
  float w[12];
  const float* dwp = dt_w + ((long)(k * 384) + d) * 12;
  #pragma unroll
  for (int r = 0; r < 12; r++) w[r] = dwp[r];
  float db = dt_b[k * 384 + d];
  long base = ((long)bk << 12) + chunk * 32;
  #pragma unroll 4
  for (int t = 0; t < 32; t++) {
    const float4* dq = (const float4*)(dtsS + (base + t) * 12);
    float4 q0 = dq[0], q1 = dq[1], q2 = dq[2];
    float x = db + q0.x * w[0] + q0.y * w[1] + q0.z * w[2] + q0.w * w[3]
                 + q1.x * w[4] + q1.y * w[5] + q1.z * w[6] + q1.w * w[7]
                 + q2.x * w[8] + q2.y * w[9] + q2.z * w[10] + q2.w * w[11];
    float e = __expf(x);
    float delta = (x > 15.f) ? x : __logf(1.f + e);
    dpre[(base + t) * 384 + d] = __float2half(delta);
  }
}

// powers: pws[n] = r^(n+1), log-depth pairing
__device__ __forceinline__ void pow16(float r, float* pws) {
  pws[0] = r;
  #pragma unroll
  for (int n = 1; n < 16; n++) {
    int m = n + 1, c = (m + 1) / 2, f = m - c;
    pws[n] = pws[c - 1] * pws[f - 1];
  }
}

// ---------------- scan pass 0: 128 segments x 32 steps; E[16] + scalar cumDelta ----------------
__global__ __launch_bounds__(384) void k_scan0(
    const __half* __restrict__ dpre, const float* __restrict__ BCs,
    const __hip_bfloat16* __restrict__ xcb,
    const float* __restrict__ A_logs,
    float* __restrict__ Eb, float* __restrict__ Dend) {
  int bid = blockIdx.x;
  int s = bid & 127, bk = bid >> 7;
  int k = bk & 3, b = bk >> 2;
  int d = threadIdx.x;
  const float* al = A_logs + ((long)(k * 384) + d) * 16;
  bool pw = true;
  float av[16];
  #pragma unroll
  for (int n = 0; n < 16; n++) {
    float a = __expf(al[n]);
    av[n] = -a;
    pw = pw && (fabsf(a - (float)(n + 1)) < 1e-3f);
  }
  float h[16];
  #pragma unroll
  for (int n = 0; n < 16; n++) h[n] = 0.f;
  float cum = 0.f;
  long bpk = (long)bk << 12;
  long bpix = (long)(b << 12);

  if (pw) {
    #pragma unroll 4
    for (int t = 0; t < 32; t++) {
      int p = dir_pix(k, s * 32 + t);
      float delta = __half2float(dpre[(bpk + p) * 384 + d]);
      float u = __bfloat162float(xcb[(bpix + p) * 384 + d]);
      cum += delta;
      float du = delta * u;
      float rr = __expf(-delta);
      float pws[16]; pow16(rr, pws);
      const float4* Bq = (const float4*)(BCs + (bpk + p) * 32);
      float4 b0 = Bq[0], b1 = Bq[1], b2 = Bq[2], b3 = Bq[3];
      float Bl[16] = {b0.x, b0.y, b0.z, b0.w, b1.x, b1.y, b1.z, b1.w,
                      b2.x, b2.y, b2.z, b2.w, b3.x, b3.y, b3.z, b3.w};
      #pragma unroll
      for (int n = 0; n < 16; n++) h[n] = pws[n] * h[n] + du * Bl[n];
    }
  } else {
    for (int t = 0; t < 32; t++) {
      int p = dir_pix(k, s * 32 + t);
      float delta = __half2float(dpre[(bpk + p) * 384 + d]);
      float u = __bfloat162float(xcb[(bpix + p) * 384 + d]);
      cum += delta;
      float du = delta * u;
      const float4* Bq = (const float4*)(BCs + (bpk + p) * 32);
      float4 b0 = Bq[0], b1 = Bq[1], b2 = Bq[2], b3 = Bq[3];
      float Bl[16] = {b0.x, b0.y, b0.z, b0.w, b1.x, b1.y, b1.z, b1.w,
                      b2.x, b2.y, b2.z, b2.w, b3.x, b3.y, b3.z, b3.w};
      #pragma unroll
      for (int n = 0; n < 16; n++) {
        float dA = __expf(delta * av[n]);
        h[n] = dA * h[n] + du * Bl[n];
      }
    }
  }
  long g = (long)bk * 128 + s;
  float* Ep = Eb + g * 6144 + d * 16;
  #pragma unroll
  for (int n = 0; n < 16; n++) Ep[n] = h[n];
  Dend[g * 384 + d] = cum;
}

// ---------------- combine: Kogge-Stone over 128 segments; pow16 trick ----------------
__global__ __launch_bounds__(128) void k_combine(float* __restrict__ Eb,
                                                 const float* __restrict__ Dend,
                                                 const float* __restrict__ A_logs) {
  int bid = blockIdx.x;            // bk*384 + d, 3072 blocks
  int bk = bid / 384;
  int d = bid - bk * 384;
  int k = bk & 3;
  int s = threadIdx.x;             // segment 0..127
  const float* al = A_logs + ((long)(k * 384) + d) * 16;
  bool pw = true;
  float av[16];
  #pragma unroll
  for (int n = 0; n < 16; n++) {
    float a = __expf(al[n]);
    av[n] = -a;
    pw = pw && (fabsf(a - (float)(n + 1)) < 1e-3f);
  }

  long ebase = ((long)bk * 128 + s) * 6144 + d * 16;
  float e[16];
  *(float4*)&e[0]  = *(const float4*)&Eb[ebase + 0];
  *(float4*)&e[4]  = *(const float4*)&Eb[ebase + 4];
  *(float4*)&e[8]  = *(const float4*)&Eb[ebase + 8];
  *(float4*)&e[12] = *(const float4*)&Eb[ebase + 12];
  float sig = Dend[((long)bk * 128 + s) * 384 + d];

  __shared__ float sE[128][17];    // [s][0]=sigma, [s][1..16]=e
  sE[s][0] = sig;
  #pragma unroll
  for (int n = 0; n < 16; n++) sE[s][1 + n] = e[n];
  __syncthreads();

  for (int o = 1; o < 128; o <<= 1) {
    float ps = 0.f, pe[16];
    bool act = (s >= o);
    if (act) {
      ps = sE[s - o][0];
      #pragma unroll
      for (int n = 0; n < 16; n++) pe[n] = sE[s - o][1 + n];
    }
    __syncthreads();
    if (act) {
      if (pw) {
        float rc = __expf(-sig);
        float pwr[16]; pow16(rc, pwr);      // pwr[n] = exp(av[n]*sig), av[n]=-(n+1)
        #pragma unroll
        for (int n = 0; n < 16; n++) e[n] += pwr[n] * pe[n];
      } else {
        #pragma unroll
        for (int n = 0; n < 16; n++) e[n] += __expf(av[n] * sig) * pe[n];
      }
      sig += ps;
      sE[s][0] = sig;
      #pragma unroll
      for (int n = 0; n < 16; n++) sE[s][1 + n] = e[n];
    }
    __syncthreads();
  }

  float ho[16];
  if (s == 0) {
    #pragma unroll
    for (int n = 0; n < 16; n++) ho[n] = 0.f;
  } else {
    #pragma unroll
    for (int n = 0; n < 16; n++) ho[n] = sE[s - 1][1 + n];
  }
  *(float4*)&Eb[ebase + 0]  = *(float4*)&ho[0];
  *(float4*)&Eb[ebase + 4]  = *(float4*)&ho[4];
  *(float4*)&Eb[ebase + 8]  = *(float4*)&ho[8];
  *(float4*)&Eb[ebase + 12] = *(float4*)&ho[12];
}

// ---------------- scan pass 1: full recurrence from h_in (in Eb) ----------------
// ATOMIC=0: store y bf16 into per-direction plane ybufB. ATOMIC=1: fp32 atomicAdd ysum.
template <int ATOMIC>
__global__ __launch_bounds__(384) void k_scan1(
    const __half* __restrict__ dpre, const float* __restrict__ BCs,
    const __hip_bfloat16* __restrict__ xcb,
    const float* __restrict__ A_logs, const float* __restrict__ Eb,
    __hip_bfloat16* __restrict__ ybufB, float* __restrict__ ysum) {
  int bid = blockIdx.x;
  int s = bid & 127, bk = bid >> 7;
  int k = bk & 3, b = bk >> 2;
  int d = threadIdx.x;
  const float* al = A_logs + ((long)(k * 384) + d) * 16;
  bool pw = true;
  float av[16];
  #pragma unroll
  for (int n = 0; n < 16; n++) {
    float a = __expf(al[n]);
    av[n] = -a;
    pw = pw && (fabsf(a - (float)(n + 1)) < 1e-3f);
  }
  float h[16];
  const float* hp = Eb + ((long)bk * 128 + s) * 6144 + d * 16;
  #pragma unroll
  for (int n = 0; n < 16; n++) h[n] = hp[n];
  long bpk = (long)bk << 12;
  long bpix = (long)(b << 12);

  if (pw) {
    #pragma unroll 4
    for (int t = 0; t < 32; t++) {
      int p = dir_pix(k, s * 32 + t);
      float delta = __half2float(dpre[(bpk + p) * 384 + d]);
      float u = __bfloat162float(xcb[(bpix + p) * 384 + d]);
      float du = delta * u;
      float rr = __expf(-delta);
      float pws[16]; pow16(rr, pws);
      const float4* Bq = (const float4*)(BCs + (bpk + p) * 32);
      float4 b0 = Bq[0], b1 = Bq[1], b2 = Bq[2], b3 = Bq[3];
      float Bl[16] = {b0.x, b0.y, b0.z, b0.w, b1.x, b1.y, b1.z, b1.w,
                      b2.x, b2.y, b2.z, b2.w, b3.x, b3.y, b3.z, b3.w};
      const float4* Cq = Bq + 4;
      float4 c0 = Cq[0], c1 = Cq[1], c2 = Cq[2], c3 = Cq[3];
      float Cl[16] = {c0.x, c0.y, c0.z, c0.w, c1.x, c1.y, c1.z, c1.w,
                      c2.x, c2.y, c2.z, c2.w, c3.x, c3.y, c3.z, c3.w};
      float y = 0.f;
      #pragma unroll
      for (int n = 0; n < 16; n++) { h[n] = pws[n] * h[n] + du * Bl[n]; y += h[n] * Cl[n]; }
      if (ATOMIC) atomicAdd(&ysum[(bpix + p) * 384 + d], y);
      else        ybufB[(bpk + p) * 384 + d] = __float2bfloat16(y);
    }
  } else {
    for (int t = 0; t < 32; t++) {
      int p = dir_pix(k, s * 32 + t);
      float delta = __half2float(dpre[(bpk + p) * 384 + d]);
      float u = __bfloat162float(xcb[(bpix + p) * 384 + d]);
      float du = delta * u;
      const float4* Bq = (const float4*)(BCs + (bpk + p) * 32);
      float4 b0 = Bq[0], b1 = Bq[1], b2 = Bq[2], b3 = Bq[3];
      float Bl[16] = {b0.x, b0.y, b0.z, b0.w, b1.x, b1.y, b1.z, b1.w,
                      b2.x, b2.y, b2.z, b2.w, b3.x, b3.y, b3.z, b3.w};
      const float4* Cq = Bq + 4;
      float4 c0 = Cq[0], c1 = Cq[1], c2 = Cq[2], c3 = Cq[3];
      float Cl[16] = {c0.x, c0.y, c0.z, c0.w, c1.x, c1.y, c1.z, c1.w,
                      c2.x, c2.y, c2.z, c2.w, c3.x, c3.y, c3.z, c3.w};
      float y = 0.f;
      #pragma unroll
      for (int n = 0; n < 16; n++) {
        float dA = __expf(delta * av[n]);
        h[n] = dA * h[n] + du * Bl[n];
        y += h[n] * Cl[n];
      }
      if (ATOMIC) atomicAdd(&ysum[(bpix + p) * 384 + d], y);
      else        ybufB[(bpk + p) * 384 + d] = __float2bfloat16(y);
    }
  }
}

// ---------------- merge: y + D-skip(bf16 xcb) + out-LN + silu(z bf16) -> bf16 ----------------
template <int GATHER>
__global__ __launch_bounds__(384) void k_merge(const __hip_bfloat16* __restrict__ yinB,
                                               const float* __restrict__ yinF,
                                               const __hip_bfloat16* __restrict__ xcb,
                                               const __hip_bfloat16* __restrict__ zbufB,
                                               const float* __restrict__ Ds,
                                               const float* __restrict__ g,
                                               const float* __restrict__ be,
                                               __hip_bfloat16* __restrict__ yactb) {
  int row = blockIdx.x;
  int d = threadIdx.x;
  float v;
  if (GATHER) {
    int b = row >> 12, p = row & 4095;
    long base = ((long)(b << 2) << 12) + p;  // plane (b*4+k)*4096 + p
    v = __bfloat162float(yinB[base * 384 + d])
      + __bfloat162float(yinB[(base + 4096) * 384 + d])
      + __bfloat162float(yinB[(base + 8192) * 384 + d])
      + __bfloat162float(yinB[(base + 12288) * 384 + d]);
  } else {
    v = yinF[(long)row * 384 + d];
  }
  float sd = Ds[d] + Ds[384 + d] + Ds[768 + d] + Ds[1152 + d];
  v += __bfloat162float(xcb[(long)row * 384 + d]) * sd;
  float s1 = v, s2 = v * v;
  #pragma unroll
  for (int o = 32; o > 0; o >>= 1) { s1 += __shfl_xor(s1, o); s2 += __shfl_xor(s2, o); }
  __shared__ float r1[6], r2[6];
  int wv = threadIdx.x >> 6;
  if ((threadIdx.x & 63) == 0) { r1[wv] = s1; r2[wv] = s2; }
  __syncthreads();
  float S1 = 0.f, S2 = 0.f;
  #pragma unroll
  for (int i = 0; i < 6; i++) { S1 += r1[i]; S2 += r2[i]; }
  float mu = S1 * (1.f / 384.f);
  float var = S2 * (1.f / 384.f) - mu * mu;
  float rr = rsqrtf(var + 1e-5f);
  float yn = (v - mu) * rr * g[d] + be[d];
  float z = __bfloat162float(zbufB[(long)row * 384 + d]);
  float sg = z / (1.f + __expf(-z));
  yactb[(long)row * 384 + d] = __float2bfloat16(yn * sg);
}

extern "C" void kernel_launch(void* const* d_in, const int* in_sizes, int n_in,
                              void* d_out, int out_size, void* d_ws, size_t ws_size,
                              hipStream_t stream) {
  const float* input      = (const float*)d_in[0];
  const float* norm_g     = (const float*)d_in[1];
  const float* norm_b     = (const float*)d_in[2];
  const float* in_proj_w  = (const float*)d_in[3];
  const float* conv_w     = (const float*)d_in[4];
  const float* conv_b     = (const float*)d_in[5];
  const float* x_proj_w   = (const float*)d_in[6];
  const float* dt_w       = (const float*)d_in[7];
  const float* dt_b       = (const float*)d_in[8];
  const float* A_logs     = (const float*)d_in[9];
  const float* Ds         = (const float*)d_in[10];
  const float* out_norm_g = (const float*)d_in[11];
  const float* out_norm_b = (const float*)d_in[12];
  const float* out_proj_w = (const float*)d_in[13];
  float* out = (float*)d_out;

  // plane path total = 27,934,720 floats (~112 MB); atomic fallback = 24,788,992 (~99 MB)
  bool big = ws_size >= (size_t)27934720 * 4;

  float* ws = (float*)d_ws;
  long o = 0;
  __hip_bfloat16* xnb   = (__hip_bfloat16*)(ws + o); o += 786432;   // 8192x192 bf16
  __hip_bfloat16* xbufB = (__hip_bfloat16*)(ws + o); o += 1572864;  // 8192x384 bf16
  __hip_bfloat16* zbufB = (__hip_bfloat16*)(ws + o); o += 1572864;
  __hip_bfloat16* xcb   = (__hip_bfloat16*)(ws + o); o += 1572864;
  __hip_bfloat16* Wt1   = (__hip_bfloat16*)(ws + o); o += 73728;    // 768x192 bf16
  __hip_bfloat16* Wt2   = (__hip_bfloat16*)(ws + o); o += 36864;
  __hip_bfloat16* Wt3   = (__hip_bfloat16*)(ws + o); o += 36864;
  float* dtsS           = ws + o;                    o += 393216;   // (BK,p,12) pixel order
  float* BCs            = ws + o;                    o += 1048576;  // (BK,p,32): B|C interleaved
  __half* dpre          = (__half*)(ws + o);         o += 6291456;  // (BK,p,384) fp16 delta
  float* Eb             = ws + o;                    o += 6291456;  // (1024 segs, 6144)
  float* Dend           = ws + o;                    o += 393216;   // (1024, 384)
  __hip_bfloat16* ybufB = (__hip_bfloat16*)(ws + o);
  float* ysum           = ws + o;                    o += big ? 6291456 : 3145728;
  __hip_bfloat16* yactb = (__hip_bfloat16*)(ws + o); o += 1572864;

  k_ln<<<dim3(2048), dim3(256), 0, stream>>>(input, norm_g, norm_b, xnb);
  k_packw<<<dim3(1152), dim3(256), 0, stream>>>(in_proj_w, x_proj_w, out_proj_w, Wt1, Wt2, Wt3);
  k_gemm_mfma<2, 128><<<dim3(6, 128), dim3(256), 0, stream>>>(xnb, Wt1, nullptr, nullptr, xbufB, zbufB,
                                                              nullptr, nullptr, 8192, 768, 192);
  k_conv<<<dim3(2048), dim3(384), 0, stream>>>(xbufB, conv_w, conv_b, xcb);
  k_gemm_mfma<3, 64><<<dim3(3, 128), dim3(256), 0, stream>>>(xcb, Wt2, nullptr, nullptr, nullptr, nullptr,
                                                             dtsS, BCs, 8192, 192, 384);
  k_dt<<<dim3(1024), dim3(384), 0, stream>>>(dtsS, dt_w, dt_b, dpre);
  k_scan0<<<dim3(1024), dim3(384), 0, stream>>>(dpre, BCs, xcb, A_logs, Eb, Dend);
  k_combine<<<dim3(3072), dim3(128), 0, stream>>>(Eb, Dend, A_logs);
  if (big) {
    k_scan1<0><<<dim3(1024), dim3(384), 0, stream>>>(dpre, BCs, xcb, A_logs, Eb, ybufB, nullptr);
    k_merge<1><<<dim3(8192), dim3(384), 0, stream>>>(ybufB, nullptr, xcb, zbufB, Ds,
                                                     out_norm_g, out_norm_b, yactb);
  } else {
    hipMemsetAsync(ysum, 0, (size_t)3145728 * 4, stream);
    k_scan1<1><<<dim3(1024), dim3(384), 0, stream>>>(dpre, BCs, xcb, A_logs, Eb, nullptr, ysum);
    k_merge<0><<<dim3(8192), dim3(384), 0, stream>>>(nullptr, ysum, xcb, zbufB, Ds,
                                                     out_norm_g, out_norm_b, yactb);
  }
  k_gemm_mfma<1, 64><<<dim3(3, 128), dim3(256), 0, stream>>>(yactb, Wt3, input, out, nullptr, nullptr,
                                                             nullptr, nullptr, 8192, 192, 384);
}